// Round 4
// baseline (935.102 us; speedup 1.0000x reference)
//
#include <hip/hip_runtime.h>
#include <hip/hip_cooperative_groups.h>

namespace cg = cooperative_groups;

// GeometryTransformation: backproject(theta=0) -> 2x resblock(conv3d 16->16 3^3,
// InstanceNorm, ReLU, residual) -> forward-project at theta in {0, pi/2}.
//
// Round-12: one persistent cooperative kernel. R11 showed per-layer WORK is
// ~10us but layers cost ~30us: the remaining term is the 6 kernel boundaries
// (full drain + relaunch + cold ramp each). fused_k runs 1024 blocks x 256
// (4/CU co-resident; LDS 27.9KB, VGPR capped 128) and replaces boundaries
// with grid.sync(). Each block: 1 prep unit, then per layer {1 interior unit
// + 1 mini unit}, then fproj1 (blk<256) / fproj2 (blk<128). Phase bodies are
// R11's verbatim (template flags -> block-uniform runtime flags): math is
// bit-identical (absmax 4.0 lineage). Falls back to the R11 multi-kernel
// path if cooperative launch is rejected.

typedef unsigned short u16;
typedef unsigned int   u32;
using s16x8 = __attribute__((ext_vector_type(8))) short;
using f32x4 = __attribute__((ext_vector_type(4))) float;

#define IN_ELEMS 262144        // 128*128*16 fp32 interior
#define MN_ELEMS 4194304       // 128*128*16*16 u16 mini
#define WS_NEED  28508480ull

__device__ __forceinline__ float bf2f(u16 h) {
    union { u32 u; float f; } v; v.u = ((u32)h) << 16; return v.f;
}
__device__ __forceinline__ u16 f2bf(float f) {
    union { float f; u32 u; } v; v.f = f;
    u32 u = v.u;
    return (u16)((u + 0x7fffu + ((u >> 16) & 1u)) >> 16);
}
__device__ __forceinline__ float ldin(const void* p, int i, int bf) {
    return bf ? bf2f(((const u16*)p)[i]) : ((const float*)p)[i];
}
__device__ __forceinline__ u16 ldbf(const void* p, int i, int bf) {
    return bf ? ((const u16*)p)[i] : f2bf(((const float*)p)[i]);
}
__device__ __forceinline__ void unpack8(uint4 a, float* f) {
    u32 w[4] = {a.x, a.y, a.z, a.w};
#pragma unroll
    for (int i = 0; i < 4; i++) {
        f[2*i]   = bf2f((u16)(w[i] & 0xffff));
        f[2*i+1] = bf2f((u16)(w[i] >> 16));
    }
}
__device__ __forceinline__ void unpack4(uint2 a, float* f) {
    f[0] = bf2f((u16)(a.x & 0xffff)); f[1] = bf2f((u16)(a.x >> 16));
    f[2] = bf2f((u16)(a.y & 0xffff)); f[3] = bf2f((u16)(a.y >> 16));
}

// Sum the 8 contention-spread stat banks -> sA[0..15]=mean, sA[16..31]=rstd.
__device__ __forceinline__ void stat8(const float* __restrict__ stP, int tid,
                                      float* __restrict__ sA)
{
    const float inv = 1.f / 2097152.f;
    int c = tid & 15;
    float ssum = 0.f, qsum = 0.f;
#pragma unroll
    for (int b2 = 0; b2 < 8; b2++) {
        ssum += stP[b2 * 32 + c];
        qsum += stP[b2 * 32 + 16 + c];
    }
    float m = ssum * inv;
    sA[tid] = (tid < 16) ? m : rsqrtf(qsum * inv - m * m + 1e-5f);
}

__global__ void sentinel_k(u16* __restrict__ out, int n)
{
    int i = blockIdx.x * 256 + threadIdx.x;
    if (i < n) out[i] = 0x4640;
}

// ===========================================================================
// Fused persistent cooperative kernel.
// ===========================================================================
struct KP {
    const void *w0, *w1, *w2, *w3, *b0, *b1, *b2, *b3, *proj;
    float *I_A, *I_B, *I_XB;
    u16   *M_A, *M_B, *M_XB;
    float *st, *biasf, *w2d, *P, *PS, *P0;
    u16   *afrag;
    void  *out;
};

__global__ __launch_bounds__(256, 4) void fused_k(KP gp)
{
    cg::grid_group grid = cg::this_grid();
    __shared__ __align__(16) char smem_raw[27904];
    const int tid = threadIdx.x;
    const int blk = blockIdx.x;

    // dtype sniff (local, every block)
    const u16* pp = (const u16*)gp.w0;
    int cnt = 0;
    for (int i = 0; i < 32; i++) {
        int e = (pp[2 * i] >> 7) & 0xFF;
        if (e >= 64 && e <= 130) cnt++;
    }
    const int bf = (cnt >= 24) ? 1 : 0;
    const void* WS[4] = {gp.w0, gp.w1, gp.w2, gp.w3};
    const void* BS[4] = {gp.b0, gp.b1, gp.b2, gp.b3};

    // ---------------- phase 0: prep ----------------
    if (blk < 18) {
        int gi = blk * 256 + tid;             // < 4608
        int L = gi / 1152, r = gi - L * 1152;
        int fi = r >> 6, l = r & 63;
        int kzky = fi >> 1, grp = fi & 1;
        int kz = kzky / 3, ky = kzky % 3;
        int n = l & 15, g = l >> 4, h = g & 1, kxs = g >> 1;
        int kx = grp * 2 + kxs;
        u16 v[8];
#pragma unroll
        for (int e = 0; e < 8; e++) {
            int ci = h * 8 + e;
            v[e] = (kx <= 2) ? ldbf(WS[L], n * 432 + ci * 27 + kz * 9 + ky * 3 + kx, bf)
                             : (u16)0;
        }
#pragma unroll
        for (int e = 0; e < 8; e++) gp.afrag[gi * 8 + e] = v[e];
    } else if (blk == 18) {
        for (int i = tid; i < 1024; i += 256) gp.st[i] = 0.f;
        if (tid < 64) gp.biasf[tid] = ldin(BS[tid >> 4], tid & 15, bf);
    } else if (blk < 99) {
        int i = (blk - 19) * 256 + tid;       // < 20480: P|PS|P0 contiguous
        gp.P[i] = 0.f;
    } else if (blk < 135) {
        int gi = (blk - 99) * 256 + tid;      // < 9216
        int L = gi / 2304, r = gi - L * 2304;
        int tap = r >> 8, ci = (r >> 4) & 15, co = r & 15;
        int kz = tap / 3, ky = tap % 3;
        float s = 0.f;
#pragma unroll
        for (int kx = 0; kx < 3; kx++)
            s += ldin(WS[L], (co * 16 + ci) * 27 + kz * 9 + ky * 3 + kx, bf);
        gp.w2d[gi] = s;
    } else if (blk < 647) {
        const int bb = blk - 135;
        const int d = bb >> 2;
        const int ys = (bb & 3) * 32;
        for (int i = tid; i < 512; i += 256) {
            int y = ys + (i >> 4), c = i & 15;
            gp.I_A[(d * 128 + y) * 16 + c] = ldin(gp.proj, c * 16384 + d * 128 + y, bf);
        }
        for (int i = tid; i < 1024; i += 256) {
            int y = ys + (i >> 5), x = (i >> 1) & 15, hh = i & 1;
            bool on = (x <= 4) | (x == 7) | (x >= 8 && x < 12);
            u32 pw[4] = {0u, 0u, 0u, 0u};
            if (on) {
#pragma unroll
                for (int j = 0; j < 4; j++) {
                    int c0 = hh * 8 + 2 * j;
                    u16 a  = f2bf(ldin(gp.proj, c0 * 16384 + d * 128 + y, bf));
                    u16 b2 = f2bf(ldin(gp.proj, (c0 + 1) * 16384 + d * 128 + y, bf));
                    pw[j] = (u32)a | ((u32)b2 << 16);
                }
            }
            *(uint4*)(gp.M_A + ((d * 128 + y) << 8) + (x << 4) + hh * 8) =
                make_uint4(pw[0], pw[1], pw[2], pw[3]);
        }
    }
    grid.sync();

    // ---------------- layers ----------------
    for (int ly = 0; ly < 4; ++ly) {
        const float *Iin; const u16 *Min;
        float *Iout; u16 *Mout;
        float *IXBw = nullptr; u16 *MXBw = nullptr;
        if (ly == 0)      { Iin = gp.I_A; Min = gp.M_A; Iout = gp.I_B; Mout = gp.M_B; }
        else if (ly == 1) { Iin = gp.I_B; Min = gp.M_B; Iout = gp.I_A; Mout = gp.M_A; }
        else if (ly == 2) { Iin = gp.I_A; Min = gp.M_A; Iout = gp.I_B; Mout = gp.M_B;
                            IXBw = gp.I_XB; MXBw = gp.M_XB; }
        else              { Iin = gp.I_B; Min = gp.M_B; Iout = gp.I_A; Mout = gp.M_A; }
        const int NORM = (ly > 0), RES = (ly == 2), WXB = (ly == 2);
        const float* stP = gp.st + (ly > 0 ? (ly - 1) * 256 : 0);
        float* stO = gp.st + ly * 256;
        const float* w2dL  = gp.w2d  + ly * 2304;
        const u16*   afragL= gp.afrag + ly * 9216;
        const float* biasL = gp.biasf + ly * 16;
        const int bank = (blk & 7) * 32;

        // ---- interior unit (blk = d*8 + y-slice) ----
        {
            float* smem = (float*)smem_raw;
            float* wsl  = smem;          // 2304
            float* pin  = smem + 2304;   // 1080 (rows padded to 20 for b128)
            float* sred = smem + 3384;   // 32
            float* sA   = smem + 3416;   // 32
            const int d  = blk >> 3;
            const int yo = (blk & 7) * 16;
            if (tid < 32) {
                sred[tid] = 0.f;
                if (NORM) stat8(stP, tid, sA);
            }
            for (int i = tid; i < 576; i += 256)
                *(float4*)(wsl + i * 4) = *(const float4*)(w2dL + i * 4);
            if (NORM) __syncthreads();   // sA ready before pin staging
            for (int i = tid; i < 864; i += 256) {
                int pln = i / 288, r = i - pln * 288;
                int row = r >> 4, c = r & 15;
                int zz = d + pln - 1, gy = yo + row - 1;
                float v = 0.f;
                if ((unsigned)zz < 128u && (unsigned)gy < 128u) {
                    v = Iin[(zz * 128 + gy) * 16 + c];
                    if (NORM) {
                        float res = RES ? ldin(gp.proj, c * 16384 + zz * 128 + gy, bf) : 0.f;
                        v = fmaxf((v - sA[c]) * sA[16 + c] + res, 0.f);
                    }
                    if (WXB && pln == 1 && row >= 1 && row <= 16)
                        IXBw[(d * 128 + gy) * 16 + c] = v;
                }
                pin[pln * 360 + row * 20 + c] = v;
            }
            __syncthreads();

            const int c = tid & 15, yl = tid >> 4;   // 16 c x 16 y
            float acc = biasL[c];
#pragma unroll
            for (int kz = 0; kz < 3; kz++) {
#pragma unroll
                for (int ky = 0; ky < 3; ky++) {
                    const float4* rowb = (const float4*)(pin + kz * 360 + (yl + ky) * 20);
                    const float* wrow = wsl + (kz * 3 + ky) * 256 + c;
#pragma unroll
                    for (int qd = 0; qd < 4; qd++) {
                        float4 vq = rowb[qd];
                        acc = fmaf(vq.x, wrow[(qd * 4 + 0) * 16], acc);
                        acc = fmaf(vq.y, wrow[(qd * 4 + 1) * 16], acc);
                        acc = fmaf(vq.z, wrow[(qd * 4 + 2) * 16], acc);
                        acc = fmaf(vq.w, wrow[(qd * 4 + 3) * 16], acc);
                    }
                }
            }
            Iout[(d * 128 + yo + yl) * 16 + c] = acc;
            float s = acc, q = acc * acc;
            s += __shfl_xor(s, 16, 64); s += __shfl_xor(s, 32, 64);
            q += __shfl_xor(q, 16, 64); q += __shfl_xor(q, 32, 64);
            if ((tid & 63) < 16) {
                atomicAdd(&sred[c], s);
                atomicAdd(&sred[16 + c], q);
            }
            __syncthreads();
            if (tid < 32) atomicAdd(&stO[bank + tid], 120.f * sred[tid]);
        }
        __syncthreads();   // LDS reuse guard before mini overwrites it

        // ---- mini unit (blk = yt*128 + z) ----
        {
            u16*   stage = (u16*)smem_raw;
            float* sredm = (float*)(smem_raw + 27648);
            float* sAm   = (float*)(smem_raw + 27776);
            const int z  = blk & 127;
            const int yt = blk >> 7;
            const int l = tid & 63, w = tid >> 6;
            const int n = l & 15, g = l >> 4, h = g & 1, kxs = g >> 1;
            const int y0 = yt * 16 + w * 4;
            const int y0b = yt * 16;

            if (tid < 32) {
                sredm[tid] = 0.f;
                if (NORM) stat8(stP, tid, sAm);
            }
            __syncthreads();   // sAm ready before staging

            for (int i = tid; i < 1728; i += 256) {
                int r = i >> 5, px = i & 31;
                int kz = r / 18, yr = r - kz * 18;
                int gz = z + kz - 1, gy = y0b + yr - 1;
                uint4 v = make_uint4(0u, 0u, 0u, 0u);
                bool inb = ((unsigned)gz < 128u) & ((unsigned)gy < 128u);
                if (!NORM) {
                    if (inb) v = *(const uint4*)(Min + (((gz << 7) + gy) << 8) + px * 8);
                } else {
                    int x = px >> 1, hh = px & 1;
                    bool realc = (x < 4) | (x >= 8 && x < 12);
                    bool ghost = (x == 4) | (x == 7);
                    if (inb & (realc | ghost)) {
                        float f[8];
                        if (realc) {
                            uint4 raw = *(const uint4*)(Min + (((gz << 7) + gy) << 8) + px * 8);
                            unpack8(raw, f);
                        } else {
                            const float* ip = Iin + ((gz * 128 + gy) * 16 + hh * 8);
                            float4 a  = *(const float4*)(ip);
                            float4 b2 = *(const float4*)(ip + 4);
                            f[0] = a.x;  f[1] = a.y;  f[2] = a.z;  f[3] = a.w;
                            f[4] = b2.x; f[5] = b2.y; f[6] = b2.z; f[7] = b2.w;
                        }
                        float vals[8];
#pragma unroll
                        for (int j = 0; j < 8; j++) {
                            int c = hh * 8 + j;
                            float res = RES ? ldin(gp.proj, c * 16384 + gz * 128 + gy, bf) : 0.f;
                            vals[j] = fmaxf((f[j] - sAm[c]) * sAm[16 + c] + res, 0.f);
                        }
                        u32 pw[4];
#pragma unroll
                        for (int j = 0; j < 4; j++)
                            pw[j] = (u32)f2bf(vals[2*j]) | ((u32)f2bf(vals[2*j+1]) << 16);
                        v = make_uint4(pw[0], pw[1], pw[2], pw[3]);
                    }
                    if (WXB && kz == 1 && yr >= 1 && yr <= 16)
                        *(uint4*)(MXBw + (((z << 7) + gy) << 8) + px * 8) = v;
                }
                *(uint4*)(stage + r * 256 + px * 8) = v;
            }

            s16x8 af[18];
#pragma unroll
            for (int fi = 0; fi < 18; fi++)
                af[fi] = *(const s16x8*)(afragL + (fi * 64 + l) * 8);
            f32x4 binit = *(const f32x4*)(biasL + g * 4);
            __syncthreads();

            f32x4 acc[4];
#pragma unroll
            for (int yl = 0; yl < 4; yl++) acc[yl] = binit;

            const int x0c = n + kxs - 1;
            const int x1c = x0c + 2;
            const bool v0ok = (unsigned)x0c < 16u;
            const bool v1ok = (unsigned)x1c < 16u;

#pragma unroll
            for (int kz = 0; kz < 3; kz++) {
#pragma unroll
                for (int yin = 0; yin < 6; yin++) {
                    const u16* rowp = stage + (kz * 18 + (w << 2) + yin) * 256 + h * 8;
                    uint4 q0 = make_uint4(0u, 0u, 0u, 0u);
                    uint4 q1 = make_uint4(0u, 0u, 0u, 0u);
                    if (v0ok) q0 = *(const uint4*)(rowp + (x0c << 4));
                    if (v1ok) q1 = *(const uint4*)(rowp + (x1c << 4));
                    s16x8 f0 = __builtin_bit_cast(s16x8, q0);
                    s16x8 f1 = __builtin_bit_cast(s16x8, q1);
#pragma unroll
                    for (int ky = 0; ky < 3; ky++) {
                        const int yl = yin - ky;
                        if (yl >= 0 && yl < 4) {
                            acc[yl] = __builtin_amdgcn_mfma_f32_16x16x32_bf16(af[(kz * 3 + ky) * 2],     f0, acc[yl], 0, 0, 0);
                            acc[yl] = __builtin_amdgcn_mfma_f32_16x16x32_bf16(af[(kz * 3 + ky) * 2 + 1], f1, acc[yl], 0, 0, 0);
                        }
                    }
                }
            }

            const float inc = (((n >> 2) & 1) == 0) ? 1.f : 0.f;
            float sr[4] = {0.f, 0.f, 0.f, 0.f}, qr[4] = {0.f, 0.f, 0.f, 0.f};
#pragma unroll
            for (int yl = 0; yl < 4; yl++) {
                const int gy = y0 + yl;
                u32 lo = (u32)f2bf(acc[yl][0]) | ((u32)f2bf(acc[yl][1]) << 16);
                u32 hi = (u32)f2bf(acc[yl][2]) | ((u32)f2bf(acc[yl][3]) << 16);
                *(uint2*)(Mout + (((z << 7) + gy) << 8) + (n << 4) + g * 4) = make_uint2(lo, hi);
#pragma unroll
                for (int r = 0; r < 4; r++) {
                    sr[r] += inc * acc[yl][r];
                    qr[r] = fmaf(inc * acc[yl][r], acc[yl][r], qr[r]);
                }
            }
#pragma unroll
            for (int off = 1; off < 16; off <<= 1) {
#pragma unroll
                for (int r = 0; r < 4; r++) {
                    sr[r] += __shfl_down(sr[r], off, 16);
                    qr[r] += __shfl_down(qr[r], off, 16);
                }
            }
            __syncthreads();
            if (n == 0) {
#pragma unroll
                for (int r = 0; r < 4; r++) {
                    atomicAdd(&sredm[g * 4 + r], sr[r]);
                    atomicAdd(&sredm[16 + g * 4 + r], qr[r]);
                }
            }
            __syncthreads();
            if (tid < 32) atomicAdd(&stO[bank + tid], sredm[tid]);
        }
        grid.sync();
    }

    // ---------------- fproj stage 1 (blk < 256) ----------------
    if (blk < 256) {
        float* sA = (float*)smem_raw;
        const int d = blk >> 1;
        const int half = blk & 1;
        if (tid < 32) stat8(gp.st + 768, tid, sA);
        __syncthreads();

        const int yl = tid & 63, y = half * 64 + yl;
        const int h = tid >> 6, c0 = h * 4;

        float v2d[4], row[4];
        {
            const int e = (d * 128 + y) * 16 + c0;
            float4 a = *(const float4*)(gp.I_A + e);
            float4 x = *(const float4*)(gp.I_XB + e);
            float ia[4] = {a.x, a.y, a.z, a.w};
            float xa[4] = {x.x, x.y, x.z, x.w};
#pragma unroll
            for (int cc = 0; cc < 4; cc++) {
                int c = c0 + cc;
                v2d[cc] = fmaxf((ia[cc] - sA[c]) * sA[16 + c] + xa[cc], 0.f);
                row[cc] = 120.f * v2d[cc];
            }
        }
        float colp[8][4];
#pragma unroll
        for (int j = 0; j < 8; j++) {
            const int m = (j < 4) ? j : j + 4;
            const int e = ((d * 128 + y) << 8) + (m << 4) + c0;
            float f4[4], fx[4];
            unpack4(*(const uint2*)(gp.M_A + e), f4);
            unpack4(*(const uint2*)(gp.M_XB + e), fx);
#pragma unroll
            for (int cc = 0; cc < 4; cc++) {
                int c = c0 + cc;
                float v = fmaxf((f4[cc] - sA[c]) * sA[16 + c] + fx[cc], 0.f);
                row[cc] += v;
                colp[j][cc] = v;
            }
        }
#pragma unroll
        for (int cc = 0; cc < 4; cc++) {
            int oi = ((c0 + cc) * 2) * 16384 + d * 128 + y;
            if (bf) ((u16*)gp.out)[oi] = f2bf(row[cc]); else ((float*)gp.out)[oi] = row[cc];
        }
#pragma unroll
        for (int off = 1; off < 64; off <<= 1) {
#pragma unroll
            for (int cc = 0; cc < 4; cc++) {
                v2d[cc] += __shfl_down(v2d[cc], off, 64);
#pragma unroll
                for (int j = 0; j < 8; j++)
                    colp[j][cc] += __shfl_down(colp[j][cc], off, 64);
            }
        }
        if (yl == 0) {
#pragma unroll
            for (int cc = 0; cc < 4; cc++) {
                atomicAdd(&gp.PS[d * 16 + c0 + cc], v2d[cc]);
#pragma unroll
                for (int j = 0; j < 8; j++)
                    atomicAdd(&gp.P[(d * 8 + j) * 16 + c0 + cc], colp[j][cc]);
                if (half == 0) gp.P0[d * 16 + c0 + cc] = colp[0][cc];
            }
        }
    }
    grid.sync();

    // ---------------- fproj stage 2 (blk < 128) ----------------
    if (blk < 128) {
        const int d = blk;
        for (int i = tid; i < 2048; i += 256) {
            int c = i >> 7, u = i & 127;
            float v;
            if (u == 0)        v = gp.P0[d * 16 + c];
            else if (u < 4)    v = gp.P[(d * 8 + u) * 16 + c];
            else if (u >= 124) v = gp.P[(d * 8 + (u - 120)) * 16 + c];
            else               v = gp.PS[d * 16 + c];
            int oi = (c * 2 + 1) * 16384 + d * 128 + u;
            if (bf) ((u16*)gp.out)[oi] = f2bf(v); else ((float*)gp.out)[oi] = v;
        }
    }
}

// ===========================================================================
// Fallback path: R11 multi-kernel pipeline (used if cooperative launch fails).
// ===========================================================================
__global__ __launch_bounds__(256) void wprep_prep_k(
    const void* __restrict__ w0, const void* __restrict__ w1,
    const void* __restrict__ w2, const void* __restrict__ w3,
    const void* __restrict__ b0, const void* __restrict__ b1,
    const void* __restrict__ b2, const void* __restrict__ b3,
    const void* __restrict__ proj,
    float* __restrict__ st, int* __restrict__ flag,
    float* __restrict__ biasf, float* __restrict__ w2d,
    float* __restrict__ pz, u16* __restrict__ afrag,
    float* __restrict__ I0, u16* __restrict__ M0)
{
    const int tid = threadIdx.x;
    const u16* pp = (const u16*)w0;
    int cnt = 0;
    for (int i = 0; i < 32; i++) {
        int e = (pp[2 * i] >> 7) & 0xFF;
        if (e >= 64 && e <= 130) cnt++;
    }
    const int bf = (cnt >= 24) ? 1 : 0;
    const void* WS[4] = {w0, w1, w2, w3};
    const void* BS[4] = {b0, b1, b2, b3};
    const int b = blockIdx.x;

    if (b >= 135) {
        const int bb = b - 135;
        const int d = bb >> 2;
        const int ys = (bb & 3) * 32;
        for (int i = tid; i < 512; i += 256) {
            int y = ys + (i >> 4), c = i & 15;
            I0[(d * 128 + y) * 16 + c] = ldin(proj, c * 16384 + d * 128 + y, bf);
        }
        for (int i = tid; i < 1024; i += 256) {
            int y = ys + (i >> 5), x = (i >> 1) & 15, hh = i & 1;
            bool on = (x <= 4) | (x == 7) | (x >= 8 && x < 12);
            u32 pw[4] = {0u, 0u, 0u, 0u};
            if (on) {
#pragma unroll
                for (int j = 0; j < 4; j++) {
                    int c0 = hh * 8 + 2 * j;
                    u16 a = f2bf(ldin(proj, c0 * 16384 + d * 128 + y, bf));
                    u16 bb2 = f2bf(ldin(proj, (c0 + 1) * 16384 + d * 128 + y, bf));
                    pw[j] = (u32)a | ((u32)bb2 << 16);
                }
            }
            *(uint4*)(M0 + ((d * 128 + y) << 8) + (x << 4) + hh * 8) =
                make_uint4(pw[0], pw[1], pw[2], pw[3]);
        }
        return;
    }

    if (b < 18) {
        int gi = b * 256 + tid;
        int L = gi / 1152, r = gi - L * 1152;
        int fi = r >> 6, l = r & 63;
        int kzky = fi >> 1, grp = fi & 1;
        int kz = kzky / 3, ky = kzky % 3;
        int n = l & 15, g = l >> 4, h = g & 1, kxs = g >> 1;
        int kx = grp * 2 + kxs;
        u16 v[8];
#pragma unroll
        for (int e = 0; e < 8; e++) {
            int ci = h * 8 + e;
            v[e] = (kx <= 2) ? ldbf(WS[L], n * 432 + ci * 27 + kz * 9 + ky * 3 + kx, bf)
                             : (u16)0;
        }
#pragma unroll
        for (int e = 0; e < 8; e++) afrag[gi * 8 + e] = v[e];
    } else if (b == 18) {
        for (int i = tid; i < 1024; i += 256) st[i] = 0.f;
        if (tid == 0) *flag = bf;
        if (tid < 64) biasf[tid] = ldin(BS[tid >> 4], tid & 15, bf);
    } else if (b < 99) {
        int i = (b - 19) * 256 + tid;
        pz[i] = 0.f;
    } else {
        int gi = (b - 99) * 256 + tid;
        int L = gi / 2304, r = gi - L * 2304;
        int tap = r >> 8, ci = (r >> 4) & 15, co = r & 15;
        int kz = tap / 3, ky = tap % 3;
        float s = 0.f;
#pragma unroll
        for (int kx = 0; kx < 3; kx++)
            s += ldin(WS[L], (co * 16 + ci) * 27 + kz * 9 + ky * 3 + kx, bf);
        w2d[gi] = s;
    }
}

template <int NORM, int RES, int WXB>
__global__ __launch_bounds__(256) void layer_k(
    const float* __restrict__ Iin, const u16* __restrict__ Min,
    const void* __restrict__ proj, const float* __restrict__ stP,
    const int* __restrict__ flagp,
    const float* __restrict__ w2dL, const u16* __restrict__ afragL,
    const float* __restrict__ biasL,
    float* __restrict__ Iout, u16* __restrict__ Mout,
    float* __restrict__ IXB, u16* __restrict__ MXB,
    float* __restrict__ st_out)
{
    __shared__ __align__(16) char smem_raw[27904];
    const int tid = threadIdx.x;
    const int bf = RES ? *flagp : 0;
    const int bank = (blockIdx.x & 7) * 32;

    if (blockIdx.x < 1024) {
        float* smem = (float*)smem_raw;
        float* wsl  = smem;
        float* pin  = smem + 2304;
        float* sred = smem + 3384;
        float* sA   = smem + 3416;
        const int d  = blockIdx.x >> 3;
        const int yo = (blockIdx.x & 7) * 16;
        if (tid < 32) {
            sred[tid] = 0.f;
            if (NORM) stat8(stP, tid, sA);
        }
        for (int i = tid; i < 576; i += 256)
            *(float4*)(wsl + i * 4) = *(const float4*)(w2dL + i * 4);
        if (NORM) __syncthreads();
        for (int i = tid; i < 864; i += 256) {
            int p = i / 288, r = i - p * 288;
            int row = r >> 4, c = r & 15;
            int zz = d + p - 1, gy = yo + row - 1;
            float v = 0.f;
            if ((unsigned)zz < 128u && (unsigned)gy < 128u) {
                v = Iin[(zz * 128 + gy) * 16 + c];
                if (NORM) {
                    float res = RES ? ldin(proj, c * 16384 + zz * 128 + gy, bf) : 0.f;
                    v = fmaxf((v - sA[c]) * sA[16 + c] + res, 0.f);
                }
                if (WXB && p == 1 && row >= 1 && row <= 16)
                    IXB[(d * 128 + gy) * 16 + c] = v;
            }
            pin[p * 360 + row * 20 + c] = v;
        }
        __syncthreads();

        const int c = tid & 15, yl = tid >> 4;
        float acc = biasL[c];
#pragma unroll
        for (int kz = 0; kz < 3; kz++) {
#pragma unroll
            for (int ky = 0; ky < 3; ky++) {
                const float4* rowb = (const float4*)(pin + kz * 360 + (yl + ky) * 20);
                const float* wrow = wsl + (kz * 3 + ky) * 256 + c;
#pragma unroll
                for (int qd = 0; qd < 4; qd++) {
                    float4 vq = rowb[qd];
                    acc = fmaf(vq.x, wrow[(qd * 4 + 0) * 16], acc);
                    acc = fmaf(vq.y, wrow[(qd * 4 + 1) * 16], acc);
                    acc = fmaf(vq.z, wrow[(qd * 4 + 2) * 16], acc);
                    acc = fmaf(vq.w, wrow[(qd * 4 + 3) * 16], acc);
                }
            }
        }
        Iout[(d * 128 + yo + yl) * 16 + c] = acc;
        float s = acc, q = acc * acc;
        s += __shfl_xor(s, 16, 64); s += __shfl_xor(s, 32, 64);
        q += __shfl_xor(q, 16, 64); q += __shfl_xor(q, 32, 64);
        if ((tid & 63) < 16) {
            atomicAdd(&sred[c], s);
            atomicAdd(&sred[16 + c], q);
        }
        __syncthreads();
        if (tid < 32) atomicAdd(&st_out[bank + tid], 120.f * sred[tid]);
        return;
    }

    u16*   stage = (u16*)smem_raw;
    float* sred  = (float*)(smem_raw + 27648);
    float* sA    = (float*)(smem_raw + 27776);
    const int mb = blockIdx.x - 1024;
    const int z  = mb & 127;
    const int yt = mb >> 7;
    const int l = tid & 63, w = tid >> 6;
    const int n = l & 15, g = l >> 4, h = g & 1, kxs = g >> 1;
    const int y0 = yt * 16 + w * 4;
    const int y0b = yt * 16;

    if (tid < 32) {
        sred[tid] = 0.f;
        if (NORM) stat8(stP, tid, sA);
    }
    if (NORM) __syncthreads();

    for (int i = tid; i < 1728; i += 256) {
        int r = i >> 5, p = i & 31;
        int kz = r / 18, yr = r - kz * 18;
        int gz = z + kz - 1, gy = y0b + yr - 1;
        uint4 v = make_uint4(0u, 0u, 0u, 0u);
        bool inb = ((unsigned)gz < 128u) & ((unsigned)gy < 128u);
        if (!NORM) {
            if (inb) v = *(const uint4*)(Min + (((gz << 7) + gy) << 8) + p * 8);
        } else {
            int x = p >> 1, hh = p & 1;
            bool realc = (x < 4) | (x >= 8 && x < 12);
            bool ghost = (x == 4) | (x == 7);
            if (inb & (realc | ghost)) {
                float f[8];
                if (realc) {
                    uint4 raw = *(const uint4*)(Min + (((gz << 7) + gy) << 8) + p * 8);
                    unpack8(raw, f);
                } else {
                    const float* ip = Iin + ((gz * 128 + gy) * 16 + hh * 8);
                    float4 a  = *(const float4*)(ip);
                    float4 b2 = *(const float4*)(ip + 4);
                    f[0] = a.x;  f[1] = a.y;  f[2] = a.z;  f[3] = a.w;
                    f[4] = b2.x; f[5] = b2.y; f[6] = b2.z; f[7] = b2.w;
                }
                float vals[8];
#pragma unroll
                for (int j = 0; j < 8; j++) {
                    int c = hh * 8 + j;
                    float res = RES ? ldin(proj, c * 16384 + gz * 128 + gy, bf) : 0.f;
                    vals[j] = fmaxf((f[j] - sA[c]) * sA[16 + c] + res, 0.f);
                }
                u32 pw[4];
#pragma unroll
                for (int j = 0; j < 4; j++)
                    pw[j] = (u32)f2bf(vals[2*j]) | ((u32)f2bf(vals[2*j+1]) << 16);
                v = make_uint4(pw[0], pw[1], pw[2], pw[3]);
            }
            if (WXB && kz == 1 && yr >= 1 && yr <= 16)
                *(uint4*)(MXB + (((z << 7) + gy) << 8) + p * 8) = v;
        }
        *(uint4*)(stage + r * 256 + p * 8) = v;
    }

    s16x8 af[18];
#pragma unroll
    for (int fi = 0; fi < 18; fi++)
        af[fi] = *(const s16x8*)(afragL + (fi * 64 + l) * 8);
    f32x4 binit = *(const f32x4*)(biasL + g * 4);
    __syncthreads();

    f32x4 acc[4];
#pragma unroll
    for (int yl = 0; yl < 4; yl++) acc[yl] = binit;

    const int x0c = n + kxs - 1;
    const int x1c = x0c + 2;
    const bool v0ok = (unsigned)x0c < 16u;
    const bool v1ok = (unsigned)x1c < 16u;

#pragma unroll
    for (int kz = 0; kz < 3; kz++) {
#pragma unroll
        for (int yin = 0; yin < 6; yin++) {
            const u16* rowp = stage + (kz * 18 + (w << 2) + yin) * 256 + h * 8;
            uint4 q0 = make_uint4(0u, 0u, 0u, 0u);
            uint4 q1 = make_uint4(0u, 0u, 0u, 0u);
            if (v0ok) q0 = *(const uint4*)(rowp + (x0c << 4));
            if (v1ok) q1 = *(const uint4*)(rowp + (x1c << 4));
            s16x8 f0 = __builtin_bit_cast(s16x8, q0);
            s16x8 f1 = __builtin_bit_cast(s16x8, q1);
#pragma unroll
            for (int ky = 0; ky < 3; ky++) {
                const int yl = yin - ky;
                if (yl >= 0 && yl < 4) {
                    acc[yl] = __builtin_amdgcn_mfma_f32_16x16x32_bf16(af[(kz * 3 + ky) * 2],     f0, acc[yl], 0, 0, 0);
                    acc[yl] = __builtin_amdgcn_mfma_f32_16x16x32_bf16(af[(kz * 3 + ky) * 2 + 1], f1, acc[yl], 0, 0, 0);
                }
            }
        }
    }

    const float inc = (((n >> 2) & 1) == 0) ? 1.f : 0.f;
    float sr[4] = {0.f, 0.f, 0.f, 0.f}, qr[4] = {0.f, 0.f, 0.f, 0.f};
#pragma unroll
    for (int yl = 0; yl < 4; yl++) {
        const int gy = y0 + yl;
        u32 lo = (u32)f2bf(acc[yl][0]) | ((u32)f2bf(acc[yl][1]) << 16);
        u32 hi = (u32)f2bf(acc[yl][2]) | ((u32)f2bf(acc[yl][3]) << 16);
        *(uint2*)(Mout + (((z << 7) + gy) << 8) + (n << 4) + g * 4) = make_uint2(lo, hi);
#pragma unroll
        for (int r = 0; r < 4; r++) {
            sr[r] += inc * acc[yl][r];
            qr[r] = fmaf(inc * acc[yl][r], acc[yl][r], qr[r]);
        }
    }
#pragma unroll
    for (int off = 1; off < 16; off <<= 1) {
#pragma unroll
        for (int r = 0; r < 4; r++) {
            sr[r] += __shfl_down(sr[r], off, 16);
            qr[r] += __shfl_down(qr[r], off, 16);
        }
    }
    __syncthreads();
    if (n == 0) {
#pragma unroll
        for (int r = 0; r < 4; r++) {
            atomicAdd(&sred[g * 4 + r], sr[r]);
            atomicAdd(&sred[16 + g * 4 + r], qr[r]);
        }
    }
    __syncthreads();
    if (tid < 32) atomicAdd(&st_out[bank + tid], sred[tid]);
}

__global__ __launch_bounds__(256) void fproj1_k(
    const float* __restrict__ I4, const float* __restrict__ IXB,
    const u16* __restrict__ M4, const u16* __restrict__ MXB,
    const float* __restrict__ stL, const int* __restrict__ flagp,
    void* __restrict__ out,
    float* __restrict__ P, float* __restrict__ PS, float* __restrict__ P0)
{
    __shared__ float sA[32];
    const int bf = *flagp;
    const int d = blockIdx.x >> 1;
    const int half = blockIdx.x & 1;
    const int tid = threadIdx.x;
    if (tid < 32) stat8(stL, tid, sA);
    __syncthreads();

    const int yl = tid & 63, y = half * 64 + yl;
    const int h = tid >> 6, c0 = h * 4;

    float v2d[4], row[4];
    {
        const int e = (d * 128 + y) * 16 + c0;
        float4 a = *(const float4*)(I4 + e);
        float4 x = *(const float4*)(IXB + e);
        float ia[4] = {a.x, a.y, a.z, a.w};
        float xa[4] = {x.x, x.y, x.z, x.w};
#pragma unroll
        for (int cc = 0; cc < 4; cc++) {
            int c = c0 + cc;
            v2d[cc] = fmaxf((ia[cc] - sA[c]) * sA[16 + c] + xa[cc], 0.f);
            row[cc] = 120.f * v2d[cc];
        }
    }
    float colp[8][4];
#pragma unroll
    for (int j = 0; j < 8; j++) {
        const int m = (j < 4) ? j : j + 4;
        const int e = ((d * 128 + y) << 8) + (m << 4) + c0;
        float f4[4], fx[4];
        unpack4(*(const uint2*)(M4 + e), f4);
        unpack4(*(const uint2*)(MXB + e), fx);
#pragma unroll
        for (int cc = 0; cc < 4; cc++) {
            int c = c0 + cc;
            float v = fmaxf((f4[cc] - sA[c]) * sA[16 + c] + fx[cc], 0.f);
            row[cc] += v;
            colp[j][cc] = v;
        }
    }
#pragma unroll
    for (int cc = 0; cc < 4; cc++) {
        int oi = ((c0 + cc) * 2) * 16384 + d * 128 + y;
        if (bf) ((u16*)out)[oi] = f2bf(row[cc]); else ((float*)out)[oi] = row[cc];
    }
#pragma unroll
    for (int off = 1; off < 64; off <<= 1) {
#pragma unroll
        for (int cc = 0; cc < 4; cc++) {
            v2d[cc] += __shfl_down(v2d[cc], off, 64);
#pragma unroll
            for (int j = 0; j < 8; j++)
                colp[j][cc] += __shfl_down(colp[j][cc], off, 64);
        }
    }
    if (yl == 0) {
#pragma unroll
        for (int cc = 0; cc < 4; cc++) {
            atomicAdd(&PS[d * 16 + c0 + cc], v2d[cc]);
#pragma unroll
            for (int j = 0; j < 8; j++)
                atomicAdd(&P[(d * 8 + j) * 16 + c0 + cc], colp[j][cc]);
            if (half == 0) P0[d * 16 + c0 + cc] = colp[0][cc];
        }
    }
}

__global__ __launch_bounds__(256) void fproj2_k(
    const float* __restrict__ P, const float* __restrict__ PS,
    const float* __restrict__ P0, const int* __restrict__ flagp,
    void* __restrict__ out)
{
    const int bf = *flagp;
    const int d = blockIdx.x;
    const int tid = threadIdx.x;
    for (int i = tid; i < 2048; i += 256) {
        int c = i >> 7, u = i & 127;
        float v;
        if (u == 0)        v = P0[d * 16 + c];
        else if (u < 4)    v = P[(d * 8 + u) * 16 + c];
        else if (u >= 124) v = P[(d * 8 + (u - 120)) * 16 + c];
        else               v = PS[d * 16 + c];
        int oi = (c * 2 + 1) * 16384 + d * 128 + u;
        if (bf) ((u16*)out)[oi] = f2bf(v); else ((float*)out)[oi] = v;
    }
}

extern "C" void kernel_launch(void* const* d_in, const int* in_sizes, int n_in,
                              void* d_out, int out_size, void* d_ws, size_t ws_size,
                              hipStream_t stream)
{
    if (ws_size < WS_NEED) {
        sentinel_k<<<(out_size + 255) / 256, 256, 0, stream>>>((u16*)d_out, out_size);
        return;
    }
    const void* proj = d_in[0];
    const void* w1 = d_in[1]; const void* b1 = d_in[2];
    const void* w2 = d_in[3]; const void* b2 = d_in[4];
    const void* w3 = d_in[5]; const void* b3 = d_in[6];
    const void* w4 = d_in[7]; const void* b4 = d_in[8];

    float* I_A  = (float*)d_ws;
    float* I_B  = I_A + IN_ELEMS;
    float* I_XB = I_B + IN_ELEMS;
    u16*   M_A  = (u16*)(I_XB + IN_ELEMS);
    u16*   M_B  = M_A + MN_ELEMS;
    u16*   M_XB = M_B + MN_ELEMS;
    float* st    = (float*)(M_XB + MN_ELEMS);   // 1024 (4 layers x 8 banks x 32)
    int*   flag  = (int*)(st + 1024);           // 16
    float* biasf = (float*)(flag + 16);         // 64
    float* w2d   = biasf + 64;                  // 9216
    float* P     = w2d + 9216;                  // 16384
    float* PS    = P + 16384;                   // 2048
    float* P0    = PS + 2048;                   // 2048
    u16*   afrag = (u16*)(P0 + 2048);           // 36864

    KP gp;
    gp.w0 = w1; gp.w1 = w2; gp.w2 = w3; gp.w3 = w4;
    gp.b0 = b1; gp.b1 = b2; gp.b2 = b3; gp.b3 = b4;
    gp.proj = proj;
    gp.I_A = I_A; gp.I_B = I_B; gp.I_XB = I_XB;
    gp.M_A = M_A; gp.M_B = M_B; gp.M_XB = M_XB;
    gp.st = st; gp.biasf = biasf; gp.w2d = w2d;
    gp.P = P; gp.PS = PS; gp.P0 = P0;
    gp.afrag = afrag; gp.out = d_out;

    void* args[] = {(void*)&gp};
    if (hipLaunchCooperativeKernel(fused_k, dim3(1024), dim3(256),
                                   args, 0, stream) == hipSuccess)
        return;

    // -------- fallback: R11 multi-kernel path --------
    wprep_prep_k<<<647, 256, 0, stream>>>(w1, w2, w3, w4, b1, b2, b3, b4, proj,
                                          st, flag, biasf, w2d, P, afrag, I_A, M_A);
    dim3 lg(2048), cb(256);
    layer_k<0,0,0><<<lg, cb, 0, stream>>>(I_A, M_A, proj, st, flag,
                                          w2d + 0,    afrag + 0,     biasf + 0,
                                          I_B, M_B, nullptr, nullptr, st + 0);
    layer_k<1,0,0><<<lg, cb, 0, stream>>>(I_B, M_B, proj, st + 0, flag,
                                          w2d + 2304, afrag + 9216,  biasf + 16,
                                          I_A, M_A, nullptr, nullptr, st + 256);
    layer_k<1,1,1><<<lg, cb, 0, stream>>>(I_A, M_A, proj, st + 256, flag,
                                          w2d + 4608, afrag + 18432, biasf + 32,
                                          I_B, M_B, I_XB, M_XB, st + 512);
    layer_k<1,0,0><<<lg, cb, 0, stream>>>(I_B, M_B, proj, st + 512, flag,
                                          w2d + 6912, afrag + 27648, biasf + 48,
                                          I_A, M_A, nullptr, nullptr, st + 768);
    fproj1_k<<<256, cb, 0, stream>>>(I_A, I_XB, M_A, M_XB, st + 768, flag, d_out, P, PS, P0);
    fproj2_k<<<128, cb, 0, stream>>>(P, PS, P0, flag, d_out);
}

// Round 5
// 202.677 us; speedup vs baseline: 4.6138x; 4.6138x over previous
//
#include <hip/hip_runtime.h>

// GeometryTransformation: backproject(theta=0) -> 2x resblock(conv3d 16->16 3^3,
// InstanceNorm, ReLU, residual) -> forward-project at theta in {0, pi/2}.
//
// Round-13: revert R12 (cooperative fused kernel spilled: launch_bounds(256,4)
// forced VGPR=64, ~256MB scratch traffic = the whole 868us). Back to the R11
// multi-kernel structure (201us), plus: layer-0 state build folded into L1.
// L1's staging (SRC0=1) constructs interior/mini inputs directly from proj
// with the exact f2bf/ldin packing prep used -> prep shrinks 647->135 blocks,
// deletes a 10MB write + 27MB re-read. Math identical (absmax 4.0 lineage).

typedef unsigned short u16;
typedef unsigned int   u32;
using s16x8 = __attribute__((ext_vector_type(8))) short;
using f32x4 = __attribute__((ext_vector_type(4))) float;

#define IN_ELEMS 262144        // 128*128*16 fp32 interior
#define MN_ELEMS 4194304       // 128*128*16*16 u16 mini
#define WS_NEED  28508480ull

__device__ __forceinline__ float bf2f(u16 h) {
    union { u32 u; float f; } v; v.u = ((u32)h) << 16; return v.f;
}
__device__ __forceinline__ u16 f2bf(float f) {
    union { float f; u32 u; } v; v.f = f;
    u32 u = v.u;
    return (u16)((u + 0x7fffu + ((u >> 16) & 1u)) >> 16);
}
__device__ __forceinline__ float ldin(const void* p, int i, int bf) {
    return bf ? bf2f(((const u16*)p)[i]) : ((const float*)p)[i];
}
__device__ __forceinline__ u16 ldbf(const void* p, int i, int bf) {
    return bf ? ((const u16*)p)[i] : f2bf(((const float*)p)[i]);
}
__device__ __forceinline__ void unpack8(uint4 a, float* f) {
    u32 w[4] = {a.x, a.y, a.z, a.w};
#pragma unroll
    for (int i = 0; i < 4; i++) {
        f[2*i]   = bf2f((u16)(w[i] & 0xffff));
        f[2*i+1] = bf2f((u16)(w[i] >> 16));
    }
}
__device__ __forceinline__ void unpack4(uint2 a, float* f) {
    f[0] = bf2f((u16)(a.x & 0xffff)); f[1] = bf2f((u16)(a.x >> 16));
    f[2] = bf2f((u16)(a.y & 0xffff)); f[3] = bf2f((u16)(a.y >> 16));
}

// Sum the 8 contention-spread stat banks -> sA[0..15]=mean, sA[16..31]=rstd.
__device__ __forceinline__ void stat8(const float* __restrict__ stP, int tid,
                                      float* __restrict__ sA)
{
    const float inv = 1.f / 2097152.f;
    int c = tid & 15;
    float ssum = 0.f, qsum = 0.f;
#pragma unroll
    for (int b2 = 0; b2 < 8; b2++) {
        ssum += stP[b2 * 32 + c];
        qsum += stP[b2 * 32 + 16 + c];
    }
    float m = ssum * inv;
    sA[tid] = (tid < 16) ? m : rsqrtf(qsum * inv - m * m + 1e-5f);
}

__global__ void sentinel_k(u16* __restrict__ out, int n)
{
    int i = blockIdx.x * 256 + threadIdx.x;
    if (i < n) out[i] = 0x4640;
}

// ---------------------------------------------------------------------------
// One-shot weight prep. 135 blocks:
//  0..17  : afrag[L][fi][lane][8]  (4608 lane-frags, MFMA A operands)
//  18     : st zero + flag + biasf
//  19..98 : zero P/PS/P0 (20480 floats)
//  99..134: w2d[L][tap9][ci][co] kx-summed fp32
// (layer-0 state build is now folded into L1 via SRC0.)
// ---------------------------------------------------------------------------
__global__ __launch_bounds__(256) void wprep_k(
    const void* __restrict__ w0, const void* __restrict__ w1,
    const void* __restrict__ w2, const void* __restrict__ w3,
    const void* __restrict__ b0, const void* __restrict__ b1,
    const void* __restrict__ b2, const void* __restrict__ b3,
    float* __restrict__ st, int* __restrict__ flag,
    float* __restrict__ biasf, float* __restrict__ w2d,
    float* __restrict__ pz, u16* __restrict__ afrag)
{
    const int tid = threadIdx.x;
    const u16* pp = (const u16*)w0;
    int cnt = 0;
    for (int i = 0; i < 32; i++) {
        int e = (pp[2 * i] >> 7) & 0xFF;
        if (e >= 64 && e <= 130) cnt++;
    }
    const int bf = (cnt >= 24) ? 1 : 0;
    const void* WS[4] = {w0, w1, w2, w3};
    const void* BS[4] = {b0, b1, b2, b3};
    const int b = blockIdx.x;

    if (b < 18) {
        int gi = b * 256 + tid;               // < 4608
        int L = gi / 1152, r = gi - L * 1152;
        int fi = r >> 6, l = r & 63;
        int kzky = fi >> 1, grp = fi & 1;
        int kz = kzky / 3, ky = kzky % 3;
        int n = l & 15, g = l >> 4, h = g & 1, kxs = g >> 1;
        int kx = grp * 2 + kxs;
        u16 v[8];
#pragma unroll
        for (int e = 0; e < 8; e++) {
            int ci = h * 8 + e;
            v[e] = (kx <= 2) ? ldbf(WS[L], n * 432 + ci * 27 + kz * 9 + ky * 3 + kx, bf)
                             : (u16)0;
        }
#pragma unroll
        for (int e = 0; e < 8; e++) afrag[gi * 8 + e] = v[e];
    } else if (b == 18) {
        for (int i = tid; i < 1024; i += 256) st[i] = 0.f;
        if (tid == 0) *flag = bf;
        if (tid < 64) biasf[tid] = ldin(BS[tid >> 4], tid & 15, bf);
    } else if (b < 99) {
        int i = (b - 19) * 256 + tid;         // < 20480
        pz[i] = 0.f;
    } else {
        int gi = (b - 99) * 256 + tid;        // < 9216
        int L = gi / 2304, r = gi - L * 2304;
        int tap = r >> 8, ci = (r >> 4) & 15, co = r & 15;
        int kz = tap / 3, ky = tap % 3;
        float s = 0.f;
#pragma unroll
        for (int kx = 0; kx < 3; kx++)
            s += ldin(WS[L], (co * 16 + ci) * 27 + kz * 9 + ky * 3 + kx, bf);
        w2d[gi] = s;
    }
}

// ---------------------------------------------------------------------------
// Fused layer. Blocks 0..1023: interior 2D conv, block=(d, 16-y slice).
// Blocks 1024..2047: mini MFMA conv (z, yt).
// SRC0: staging builds layer-0 state directly from proj (exact prep packing).
// NORM: staging normalizes previous raw output (8-bank stats). RES: +proj.
// WXB: write XB from owned region.
// ---------------------------------------------------------------------------
template <int SRC0, int NORM, int RES, int WXB>
__global__ __launch_bounds__(256) void layer_k(
    const float* __restrict__ Iin, const u16* __restrict__ Min,
    const void* __restrict__ proj, const float* __restrict__ stP,
    const int* __restrict__ flagp,
    const float* __restrict__ w2dL, const u16* __restrict__ afragL,
    const float* __restrict__ biasL,
    float* __restrict__ Iout, u16* __restrict__ Mout,
    float* __restrict__ IXB, u16* __restrict__ MXB,
    float* __restrict__ st_out)
{
    // interior: wsl 2304 f | pin 3*18*20=1080 f | sred 32 f | sA 32 f (13792 B)
    // mini:     stage 54*256 u16 (27648 B) | sred 32 f | sA 32 f (27904 B)
    __shared__ __align__(16) char smem_raw[27904];
    const int tid = threadIdx.x;
    const int bf = (SRC0 || RES) ? *flagp : 0;
    const int bank = (blockIdx.x & 7) * 32;

    if (blockIdx.x < 1024) {
        float* smem = (float*)smem_raw;
        float* wsl  = smem;          // 2304
        float* pin  = smem + 2304;   // 1080 (rows padded to 20 for b128)
        float* sred = smem + 3384;   // 32
        float* sA   = smem + 3416;   // 32
        const int d  = blockIdx.x >> 3;
        const int yo = (blockIdx.x & 7) * 16;
        if (tid < 32) {
            sred[tid] = 0.f;
            if (NORM) stat8(stP, tid, sA);
        }
        for (int i = tid; i < 576; i += 256)
            *(float4*)(wsl + i * 4) = *(const float4*)(w2dL + i * 4);
        if (NORM) __syncthreads();           // sA ready before pin staging
        for (int i = tid; i < 864; i += 256) {
            int p = i / 288, r = i - p * 288;
            int row = r >> 4, c = r & 15;
            int zz = d + p - 1, gy = yo + row - 1;
            float v = 0.f;
            if ((unsigned)zz < 128u && (unsigned)gy < 128u) {
                if (SRC0) {
                    v = ldin(proj, c * 16384 + zz * 128 + gy, bf);
                } else {
                    v = Iin[(zz * 128 + gy) * 16 + c];
                    if (NORM) {
                        float res = RES ? ldin(proj, c * 16384 + zz * 128 + gy, bf) : 0.f;
                        v = fmaxf((v - sA[c]) * sA[16 + c] + res, 0.f);
                    }
                    if (WXB && p == 1 && row >= 1 && row <= 16)
                        IXB[(d * 128 + gy) * 16 + c] = v;
                }
            }
            pin[p * 360 + row * 20 + c] = v;
        }
        __syncthreads();

        const int c = tid & 15, yl = tid >> 4;   // 16 c x 16 y
        float acc = biasL[c];
#pragma unroll
        for (int kz = 0; kz < 3; kz++) {
#pragma unroll
            for (int ky = 0; ky < 3; ky++) {
                const float4* rowb = (const float4*)(pin + kz * 360 + (yl + ky) * 20);
                const float* wrow = wsl + (kz * 3 + ky) * 256 + c;
#pragma unroll
                for (int qd = 0; qd < 4; qd++) {
                    float4 vq = rowb[qd];
                    acc = fmaf(vq.x, wrow[(qd * 4 + 0) * 16], acc);
                    acc = fmaf(vq.y, wrow[(qd * 4 + 1) * 16], acc);
                    acc = fmaf(vq.z, wrow[(qd * 4 + 2) * 16], acc);
                    acc = fmaf(vq.w, wrow[(qd * 4 + 3) * 16], acc);
                }
            }
        }
        Iout[(d * 128 + yo + yl) * 16 + c] = acc;
        float s = acc, q = acc * acc;
        s += __shfl_xor(s, 16, 64); s += __shfl_xor(s, 32, 64);
        q += __shfl_xor(q, 16, 64); q += __shfl_xor(q, 32, 64);
        if ((tid & 63) < 16) {
            atomicAdd(&sred[c], s);
            atomicAdd(&sred[16 + c], q);
        }
        __syncthreads();
        if (tid < 32) atomicAdd(&st_out[bank + tid], 120.f * sred[tid]);
        return;
    }

    // ---------------- mini path ----------------
    u16*   stage = (u16*)smem_raw;
    float* sred  = (float*)(smem_raw + 27648);
    float* sA    = (float*)(smem_raw + 27776);
    const int mb = blockIdx.x - 1024;
    const int z  = mb & 127;
    const int yt = mb >> 7;
    const int l = tid & 63, w = tid >> 6;
    const int n = l & 15, g = l >> 4, h = g & 1, kxs = g >> 1;
    const int y0 = yt * 16 + w * 4;
    const int y0b = yt * 16;

    if (tid < 32) {
        sred[tid] = 0.f;
        if (NORM) stat8(stP, tid, sA);
    }
    if (NORM) __syncthreads();               // sA ready before staging

    // Stage 54 rows (3 z-planes x 18 y-rows), 512B each.
    // SRC0 builds rows from proj (prep's exact packing); NORM applies the
    // fused normalize (ghosts x=4,7 from interior; zeros elsewhere).
    for (int i = tid; i < 1728; i += 256) {
        int r = i >> 5, px = i & 31;
        int kz = r / 18, yr = r - kz * 18;
        int gz = z + kz - 1, gy = y0b + yr - 1;
        uint4 v = make_uint4(0u, 0u, 0u, 0u);
        bool inb = ((unsigned)gz < 128u) & ((unsigned)gy < 128u);
        if (SRC0) {
            int x = px >> 1, hh = px & 1;
            bool on = (x <= 4) | (x == 7) | (x >= 8 && x < 12);
            if (inb & on) {
                u32 pw[4];
#pragma unroll
                for (int j = 0; j < 4; j++) {
                    int c0 = hh * 8 + 2 * j;
                    u16 a  = f2bf(ldin(proj, c0 * 16384 + gz * 128 + gy, bf));
                    u16 b2 = f2bf(ldin(proj, (c0 + 1) * 16384 + gz * 128 + gy, bf));
                    pw[j] = (u32)a | ((u32)b2 << 16);
                }
                v = make_uint4(pw[0], pw[1], pw[2], pw[3]);
            }
        } else if (!NORM) {
            if (inb) v = *(const uint4*)(Min + (((gz << 7) + gy) << 8) + px * 8);
        } else {
            int x = px >> 1, hh = px & 1;
            bool realc = (x < 4) | (x >= 8 && x < 12);
            bool ghost = (x == 4) | (x == 7);
            if (inb & (realc | ghost)) {
                float f[8];
                if (realc) {
                    uint4 raw = *(const uint4*)(Min + (((gz << 7) + gy) << 8) + px * 8);
                    unpack8(raw, f);
                } else {
                    const float* ip = Iin + ((gz * 128 + gy) * 16 + hh * 8);
                    float4 a  = *(const float4*)(ip);
                    float4 b2 = *(const float4*)(ip + 4);
                    f[0] = a.x;  f[1] = a.y;  f[2] = a.z;  f[3] = a.w;
                    f[4] = b2.x; f[5] = b2.y; f[6] = b2.z; f[7] = b2.w;
                }
                float vals[8];
#pragma unroll
                for (int j = 0; j < 8; j++) {
                    int c = hh * 8 + j;
                    float res = RES ? ldin(proj, c * 16384 + gz * 128 + gy, bf) : 0.f;
                    vals[j] = fmaxf((f[j] - sA[c]) * sA[16 + c] + res, 0.f);
                }
                u32 pw[4];
#pragma unroll
                for (int j = 0; j < 4; j++)
                    pw[j] = (u32)f2bf(vals[2*j]) | ((u32)f2bf(vals[2*j+1]) << 16);
                v = make_uint4(pw[0], pw[1], pw[2], pw[3]);
            }
            if (WXB && kz == 1 && yr >= 1 && yr <= 16)
                *(uint4*)(MXB + (((z << 7) + gy) << 8) + px * 8) = v;
        }
        *(uint4*)(stage + r * 256 + px * 8) = v;
    }

    s16x8 af[18];
#pragma unroll
    for (int fi = 0; fi < 18; fi++)
        af[fi] = *(const s16x8*)(afragL + (fi * 64 + l) * 8);
    f32x4 binit = *(const f32x4*)(biasL + g * 4);
    __syncthreads();

    f32x4 acc[4];
#pragma unroll
    for (int yl = 0; yl < 4; yl++) acc[yl] = binit;

    const int x0c = n + kxs - 1;
    const int x1c = x0c + 2;
    const bool v0ok = (unsigned)x0c < 16u;
    const bool v1ok = (unsigned)x1c < 16u;

#pragma unroll
    for (int kz = 0; kz < 3; kz++) {
#pragma unroll
        for (int yin = 0; yin < 6; yin++) {
            const u16* rowp = stage + (kz * 18 + (w << 2) + yin) * 256 + h * 8;
            uint4 q0 = make_uint4(0u, 0u, 0u, 0u);
            uint4 q1 = make_uint4(0u, 0u, 0u, 0u);
            if (v0ok) q0 = *(const uint4*)(rowp + (x0c << 4));
            if (v1ok) q1 = *(const uint4*)(rowp + (x1c << 4));
            s16x8 f0 = __builtin_bit_cast(s16x8, q0);
            s16x8 f1 = __builtin_bit_cast(s16x8, q1);
#pragma unroll
            for (int ky = 0; ky < 3; ky++) {
                const int yl = yin - ky;
                if (yl >= 0 && yl < 4) {
                    acc[yl] = __builtin_amdgcn_mfma_f32_16x16x32_bf16(af[(kz * 3 + ky) * 2],     f0, acc[yl], 0, 0, 0);
                    acc[yl] = __builtin_amdgcn_mfma_f32_16x16x32_bf16(af[(kz * 3 + ky) * 2 + 1], f1, acc[yl], 0, 0, 0);
                }
            }
        }
    }

    const float inc = (((n >> 2) & 1) == 0) ? 1.f : 0.f;
    float sr[4] = {0.f, 0.f, 0.f, 0.f}, qr[4] = {0.f, 0.f, 0.f, 0.f};
#pragma unroll
    for (int yl = 0; yl < 4; yl++) {
        const int gy = y0 + yl;
        u32 lo = (u32)f2bf(acc[yl][0]) | ((u32)f2bf(acc[yl][1]) << 16);
        u32 hi = (u32)f2bf(acc[yl][2]) | ((u32)f2bf(acc[yl][3]) << 16);
        *(uint2*)(Mout + (((z << 7) + gy) << 8) + (n << 4) + g * 4) = make_uint2(lo, hi);
#pragma unroll
        for (int r = 0; r < 4; r++) {
            sr[r] += inc * acc[yl][r];
            qr[r] = fmaf(inc * acc[yl][r], acc[yl][r], qr[r]);
        }
    }
#pragma unroll
    for (int off = 1; off < 16; off <<= 1) {
#pragma unroll
        for (int r = 0; r < 4; r++) {
            sr[r] += __shfl_down(sr[r], off, 16);
            qr[r] += __shfl_down(qr[r], off, 16);
        }
    }
    __syncthreads();
    if (n == 0) {
#pragma unroll
        for (int r = 0; r < 4; r++) {
            atomicAdd(&sred[g * 4 + r], sr[r]);
            atomicAdd(&sred[16 + g * 4 + r], qr[r]);
        }
    }
    __syncthreads();
    if (tid < 32) atomicAdd(&st_out[bank + tid], sred[tid]);
}

// fproj stage 1: 256 blocks = (d, y-half). vol2 = relu((y4-m)s + xb).
__global__ __launch_bounds__(256) void fproj1_k(
    const float* __restrict__ I4, const float* __restrict__ IXB,
    const u16* __restrict__ M4, const u16* __restrict__ MXB,
    const float* __restrict__ stL, const int* __restrict__ flagp,
    void* __restrict__ out,
    float* __restrict__ P, float* __restrict__ PS, float* __restrict__ P0)
{
    __shared__ float sA[32];
    const int bf = *flagp;
    const int d = blockIdx.x >> 1;
    const int half = blockIdx.x & 1;
    const int tid = threadIdx.x;
    if (tid < 32) stat8(stL, tid, sA);
    __syncthreads();

    const int yl = tid & 63, y = half * 64 + yl;
    const int h = tid >> 6, c0 = h * 4;

    float v2d[4], row[4];
    {
        const int e = (d * 128 + y) * 16 + c0;
        float4 a = *(const float4*)(I4 + e);
        float4 x = *(const float4*)(IXB + e);
        float ia[4] = {a.x, a.y, a.z, a.w};
        float xa[4] = {x.x, x.y, x.z, x.w};
#pragma unroll
        for (int cc = 0; cc < 4; cc++) {
            int c = c0 + cc;
            v2d[cc] = fmaxf((ia[cc] - sA[c]) * sA[16 + c] + xa[cc], 0.f);
            row[cc] = 120.f * v2d[cc];
        }
    }
    float colp[8][4];
#pragma unroll
    for (int j = 0; j < 8; j++) {
        const int m = (j < 4) ? j : j + 4;
        const int e = ((d * 128 + y) << 8) + (m << 4) + c0;
        float f4[4], fx[4];
        unpack4(*(const uint2*)(M4 + e), f4);
        unpack4(*(const uint2*)(MXB + e), fx);
#pragma unroll
        for (int cc = 0; cc < 4; cc++) {
            int c = c0 + cc;
            float v = fmaxf((f4[cc] - sA[c]) * sA[16 + c] + fx[cc], 0.f);
            row[cc] += v;
            colp[j][cc] = v;
        }
    }
#pragma unroll
    for (int cc = 0; cc < 4; cc++) {
        int oi = ((c0 + cc) * 2) * 16384 + d * 128 + y;
        if (bf) ((u16*)out)[oi] = f2bf(row[cc]); else ((float*)out)[oi] = row[cc];
    }
#pragma unroll
    for (int off = 1; off < 64; off <<= 1) {
#pragma unroll
        for (int cc = 0; cc < 4; cc++) {
            v2d[cc] += __shfl_down(v2d[cc], off, 64);
#pragma unroll
            for (int j = 0; j < 8; j++)
                colp[j][cc] += __shfl_down(colp[j][cc], off, 64);
        }
    }
    if (yl == 0) {
#pragma unroll
        for (int cc = 0; cc < 4; cc++) {
            atomicAdd(&PS[d * 16 + c0 + cc], v2d[cc]);
#pragma unroll
            for (int j = 0; j < 8; j++)
                atomicAdd(&P[(d * 8 + j) * 16 + c0 + cc], colp[j][cc]);
            if (half == 0) P0[d * 16 + c0 + cc] = colp[0][cc];
        }
    }
}

// fproj stage 2: expand partials into theta=pi/2 outputs.
__global__ __launch_bounds__(256) void fproj2_k(
    const float* __restrict__ P, const float* __restrict__ PS,
    const float* __restrict__ P0, const int* __restrict__ flagp,
    void* __restrict__ out)
{
    const int bf = *flagp;
    const int d = blockIdx.x;
    const int tid = threadIdx.x;
    for (int i = tid; i < 2048; i += 256) {
        int c = i >> 7, u = i & 127;
        float v;
        if (u == 0)        v = P0[d * 16 + c];
        else if (u < 4)    v = P[(d * 8 + u) * 16 + c];
        else if (u >= 124) v = P[(d * 8 + (u - 120)) * 16 + c];
        else               v = PS[d * 16 + c];
        int oi = (c * 2 + 1) * 16384 + d * 128 + u;
        if (bf) ((u16*)out)[oi] = f2bf(v); else ((float*)out)[oi] = v;
    }
}

extern "C" void kernel_launch(void* const* d_in, const int* in_sizes, int n_in,
                              void* d_out, int out_size, void* d_ws, size_t ws_size,
                              hipStream_t stream)
{
    if (ws_size < WS_NEED) {
        sentinel_k<<<(out_size + 255) / 256, 256, 0, stream>>>((u16*)d_out, out_size);
        return;
    }
    const void* proj = d_in[0];
    const void* w1 = d_in[1]; const void* b1 = d_in[2];
    const void* w2 = d_in[3]; const void* b2 = d_in[4];
    const void* w3 = d_in[5]; const void* b3 = d_in[6];
    const void* w4 = d_in[7]; const void* b4 = d_in[8];

    float* I_A  = (float*)d_ws;
    float* I_B  = I_A + IN_ELEMS;
    float* I_XB = I_B + IN_ELEMS;
    u16*   M_A  = (u16*)(I_XB + IN_ELEMS);
    u16*   M_B  = M_A + MN_ELEMS;
    u16*   M_XB = M_B + MN_ELEMS;
    float* st    = (float*)(M_XB + MN_ELEMS);   // 1024 (4 layers x 8 banks x 32)
    int*   flag  = (int*)(st + 1024);           // 16
    float* biasf = (float*)(flag + 16);         // 64
    float* w2d   = biasf + 64;                  // 9216
    float* P     = w2d + 9216;                  // 16384
    float* PS    = P + 16384;                   // 2048
    float* P0    = PS + 2048;                   // 2048
    u16*   afrag = (u16*)(P0 + 2048);           // 36864

    wprep_k<<<135, 256, 0, stream>>>(w1, w2, w3, w4, b1, b2, b3, b4,
                                     st, flag, biasf, w2d, P, afrag);

    dim3 lg(2048), cb(256);
    // L1: conv1 on vol0, built directly from proj (SRC0).   -> B, stats st0
    layer_k<1,0,0,0><<<lg, cb, 0, stream>>>(I_A, M_A, proj, st, flag,
                                            w2d + 0,    afrag + 0,     biasf + 0,
                                            I_B, M_B, nullptr, nullptr, st + 0);
    // L2: conv2 on relu(IN_st0(y1)).      B -> A, stats st1
    layer_k<0,1,0,0><<<lg, cb, 0, stream>>>(I_B, M_B, proj, st + 0, flag,
                                            w2d + 2304, afrag + 9216,  biasf + 16,
                                            I_A, M_A, nullptr, nullptr, st + 256);
    // L3: conv3 on XB=relu(IN_st1(y2)+proj); materialize XB.  A -> B, stats st2
    layer_k<0,1,1,1><<<lg, cb, 0, stream>>>(I_A, M_A, proj, st + 256, flag,
                                            w2d + 4608, afrag + 18432, biasf + 32,
                                            I_B, M_B, I_XB, M_XB, st + 512);
    // L4: conv4 on relu(IN_st2(y3)).      B -> A, stats st3
    layer_k<0,1,0,0><<<lg, cb, 0, stream>>>(I_B, M_B, proj, st + 512, flag,
                                            w2d + 6912, afrag + 27648, biasf + 48,
                                            I_A, M_A, nullptr, nullptr, st + 768);
    // projection: raw y4 in A, residual XB
    fproj1_k<<<256, cb, 0, stream>>>(I_A, I_XB, M_A, M_XB, st + 768, flag, d_out, P, PS, P0);
    fproj2_k<<<128, cb, 0, stream>>>(P, PS, P0, flag, d_out);
}

// Round 7
// 202.637 us; speedup vs baseline: 4.6147x; 1.0002x over previous
//
#include <hip/hip_runtime.h>
#include <hip/hip_cooperative_groups.h>

namespace cg = cooperative_groups;

// GeometryTransformation: backproject(theta=0) -> 2x resblock(conv3d 16->16 3^3,
// InstanceNorm, ReLU, residual) -> forward-project at theta in {0, pi/2}.
//
// Round-16: persistent cooperative kernel, co-residency made provable.
// R14 failed because the UNCAPPED kernel (VGPR>128) made the 1024-block
// cooperative launch be REJECTED inside graph capture -> capture poisoned ->
// bench exception. Fix: grid 512 x 256, each block does 2 units per phase
// (2 blocks/CU needed: LDS 2x27.9KB ok, __launch_bounds__(256,2) caps VGPR at
// 256 -- natural ~100, no spill pressure unlike R12's 64-cap). Host gates the
// cooperative launch on a capture-safe occupancy query (cached); if it cannot
// prove >=512 co-resident blocks it runs the proven R13 multi-kernel path
// directly, so the poisoning path is unreachable.
// Math identical (absmax 4.0 lineage).

typedef unsigned short u16;
typedef unsigned int   u32;
using s16x8 = __attribute__((ext_vector_type(8))) short;
using f32x4 = __attribute__((ext_vector_type(4))) float;

#define IN_ELEMS 262144        // 128*128*16 fp32 interior
#define MN_ELEMS 4194304       // 128*128*16*16 u16 mini
#define WS_NEED  28508480ull

__device__ __forceinline__ float bf2f(u16 h) {
    union { u32 u; float f; } v; v.u = ((u32)h) << 16; return v.f;
}
__device__ __forceinline__ u16 f2bf(float f) {
    union { float f; u32 u; } v; v.f = f;
    u32 u = v.u;
    return (u16)((u + 0x7fffu + ((u >> 16) & 1u)) >> 16);
}
__device__ __forceinline__ float ldin(const void* p, int i, int bf) {
    return bf ? bf2f(((const u16*)p)[i]) : ((const float*)p)[i];
}
__device__ __forceinline__ u16 ldbf(const void* p, int i, int bf) {
    return bf ? ((const u16*)p)[i] : f2bf(((const float*)p)[i]);
}
__device__ __forceinline__ void unpack8(uint4 a, float* f) {
    u32 w[4] = {a.x, a.y, a.z, a.w};
#pragma unroll
    for (int i = 0; i < 4; i++) {
        f[2*i]   = bf2f((u16)(w[i] & 0xffff));
        f[2*i+1] = bf2f((u16)(w[i] >> 16));
    }
}
__device__ __forceinline__ void unpack4(uint2 a, float* f) {
    f[0] = bf2f((u16)(a.x & 0xffff)); f[1] = bf2f((u16)(a.x >> 16));
    f[2] = bf2f((u16)(a.y & 0xffff)); f[3] = bf2f((u16)(a.y >> 16));
}

// Sum the 8 contention-spread stat banks -> sA[0..15]=mean, sA[16..31]=rstd.
__device__ __forceinline__ void stat8(const float* __restrict__ stP, int tid,
                                      float* __restrict__ sA)
{
    const float inv = 1.f / 2097152.f;
    int c = tid & 15;
    float ssum = 0.f, qsum = 0.f;
#pragma unroll
    for (int b2 = 0; b2 < 8; b2++) {
        ssum += stP[b2 * 32 + c];
        qsum += stP[b2 * 32 + 16 + c];
    }
    float m = ssum * inv;
    sA[tid] = (tid < 16) ? m : rsqrtf(qsum * inv - m * m + 1e-5f);
}

__global__ void sentinel_k(u16* __restrict__ out, int n)
{
    int i = blockIdx.x * 256 + threadIdx.x;
    if (i < n) out[i] = 0x4640;
}

// ===========================================================================
// Fused persistent cooperative kernel: 512 blocks x 2 units per phase.
// ===========================================================================
struct KP {
    const void *w0, *w1, *w2, *w3, *b0, *b1, *b2, *b3, *proj;
    float *I_A, *I_B, *I_XB;
    u16   *M_A, *M_B, *M_XB;
    float *st, *biasf, *w2d, *P, *PS, *P0;
    u16   *afrag;
    void  *out;
};

__global__ __launch_bounds__(256, 2) void fused_k(KP gp)
{
    cg::grid_group grid = cg::this_grid();
    __shared__ __align__(16) char smem_raw[27904];
    const int tid = threadIdx.x;

    // dtype sniff (local, every block)
    const u16* pp = (const u16*)gp.w0;
    int cnt = 0;
    for (int i = 0; i < 32; i++) {
        int e = (pp[2 * i] >> 7) & 0xFF;
        if (e >= 64 && e <= 130) cnt++;
    }
    const int bf = (cnt >= 24) ? 1 : 0;
    const void* WS[4] = {gp.w0, gp.w1, gp.w2, gp.w3};
    const void* BS[4] = {gp.b0, gp.b1, gp.b2, gp.b3};

    // ---------------- phase 0: prep (units 0..646) ----------------
    for (int u = 0; u < 2; ++u) {
        const int unit = blockIdx.x * 2 + u;
        if (unit >= 647) break;
        if (unit < 18) {
            int gi = unit * 256 + tid;            // < 4608
            int L = gi / 1152, r = gi - L * 1152;
            int fi = r >> 6, l = r & 63;
            int kzky = fi >> 1, grp = fi & 1;
            int kz = kzky / 3, ky = kzky % 3;
            int n = l & 15, g = l >> 4, h = g & 1, kxs = g >> 1;
            int kx = grp * 2 + kxs;
            u16 v[8];
#pragma unroll
            for (int e = 0; e < 8; e++) {
                int ci = h * 8 + e;
                v[e] = (kx <= 2) ? ldbf(WS[L], n * 432 + ci * 27 + kz * 9 + ky * 3 + kx, bf)
                                 : (u16)0;
            }
#pragma unroll
            for (int e = 0; e < 8; e++) gp.afrag[gi * 8 + e] = v[e];
        } else if (unit == 18) {
            for (int i = tid; i < 1024; i += 256) gp.st[i] = 0.f;
            if (tid < 64) gp.biasf[tid] = ldin(BS[tid >> 4], tid & 15, bf);
        } else if (unit < 99) {
            int i = (unit - 19) * 256 + tid;      // < 20480: P|PS|P0 contiguous
            gp.P[i] = 0.f;
        } else if (unit < 135) {
            int gi = (unit - 99) * 256 + tid;     // < 9216
            int L = gi / 2304, r = gi - L * 2304;
            int tap = r >> 8, ci = (r >> 4) & 15, co = r & 15;
            int kz = tap / 3, ky = tap % 3;
            float s = 0.f;
#pragma unroll
            for (int kx = 0; kx < 3; kx++)
                s += ldin(WS[L], (co * 16 + ci) * 27 + kz * 9 + ky * 3 + kx, bf);
            gp.w2d[gi] = s;
        } else {
            const int bb = unit - 135;            // < 512
            const int d = bb >> 2;
            const int ys = (bb & 3) * 32;
            for (int i = tid; i < 512; i += 256) {
                int y = ys + (i >> 4), c = i & 15;
                gp.I_A[(d * 128 + y) * 16 + c] = ldin(gp.proj, c * 16384 + d * 128 + y, bf);
            }
            for (int i = tid; i < 1024; i += 256) {
                int y = ys + (i >> 5), x = (i >> 1) & 15, hh = i & 1;
                bool on = (x <= 4) | (x == 7) | (x >= 8 && x < 12);
                u32 pw[4] = {0u, 0u, 0u, 0u};
                if (on) {
#pragma unroll
                    for (int j = 0; j < 4; j++) {
                        int c0 = hh * 8 + 2 * j;
                        u16 a  = f2bf(ldin(gp.proj, c0 * 16384 + d * 128 + y, bf));
                        u16 b2 = f2bf(ldin(gp.proj, (c0 + 1) * 16384 + d * 128 + y, bf));
                        pw[j] = (u32)a | ((u32)b2 << 16);
                    }
                }
                *(uint4*)(gp.M_A + ((d * 128 + y) << 8) + (x << 4) + hh * 8) =
                    make_uint4(pw[0], pw[1], pw[2], pw[3]);
            }
        }
    }
    grid.sync();

    // ---------------- layers ----------------
    for (int ly = 0; ly < 4; ++ly) {
        const float *Iin; const u16 *Min;
        float *Iout; u16 *Mout;
        float *IXBw = nullptr; u16 *MXBw = nullptr;
        if (ly == 0)      { Iin = gp.I_A; Min = gp.M_A; Iout = gp.I_B; Mout = gp.M_B; }
        else if (ly == 1) { Iin = gp.I_B; Min = gp.M_B; Iout = gp.I_A; Mout = gp.M_A; }
        else if (ly == 2) { Iin = gp.I_A; Min = gp.M_A; Iout = gp.I_B; Mout = gp.M_B;
                            IXBw = gp.I_XB; MXBw = gp.M_XB; }
        else              { Iin = gp.I_B; Min = gp.M_B; Iout = gp.I_A; Mout = gp.M_A; }
        const int NORM = (ly > 0), RES = (ly == 2), WXB = (ly == 2);
        const float* stP = gp.st + (ly > 0 ? (ly - 1) * 256 : 0);
        float* stO = gp.st + ly * 256;
        const float* w2dL  = gp.w2d  + ly * 2304;
        const u16*   afragL= gp.afrag + ly * 9216;
        const float* biasL = gp.biasf + ly * 16;

        // ---- interior units (unit = d*8 + y-slice) ----
        for (int u = 0; u < 2; ++u) {
            const int unit = blockIdx.x * 2 + u;
            const int bank = (unit & 7) * 32;
            float* smem = (float*)smem_raw;
            float* wsl  = smem;          // 2304
            float* pin  = smem + 2304;   // 1080 (rows padded to 20 for b128)
            float* sred = smem + 3384;   // 32
            float* sA   = smem + 3416;   // 32
            const int d  = unit >> 3;
            const int yo = (unit & 7) * 16;
            if (tid < 32) {
                sred[tid] = 0.f;
                if (NORM) stat8(stP, tid, sA);
            }
            for (int i = tid; i < 576; i += 256)
                *(float4*)(wsl + i * 4) = *(const float4*)(w2dL + i * 4);
            if (NORM) __syncthreads();   // sA ready before pin staging
            for (int i = tid; i < 864; i += 256) {
                int pln = i / 288, r = i - pln * 288;
                int row = r >> 4, c = r & 15;
                int zz = d + pln - 1, gy = yo + row - 1;
                float v = 0.f;
                if ((unsigned)zz < 128u && (unsigned)gy < 128u) {
                    v = Iin[(zz * 128 + gy) * 16 + c];
                    if (NORM) {
                        float res = RES ? ldin(gp.proj, c * 16384 + zz * 128 + gy, bf) : 0.f;
                        v = fmaxf((v - sA[c]) * sA[16 + c] + res, 0.f);
                    }
                    if (WXB && pln == 1 && row >= 1 && row <= 16)
                        IXBw[(d * 128 + gy) * 16 + c] = v;
                }
                pin[pln * 360 + row * 20 + c] = v;
            }
            __syncthreads();

            const int c = tid & 15, yl = tid >> 4;   // 16 c x 16 y
            float acc = biasL[c];
#pragma unroll
            for (int kz = 0; kz < 3; kz++) {
#pragma unroll
                for (int ky = 0; ky < 3; ky++) {
                    const float4* rowb = (const float4*)(pin + kz * 360 + (yl + ky) * 20);
                    const float* wrow = wsl + (kz * 3 + ky) * 256 + c;
#pragma unroll
                    for (int qd = 0; qd < 4; qd++) {
                        float4 vq = rowb[qd];
                        acc = fmaf(vq.x, wrow[(qd * 4 + 0) * 16], acc);
                        acc = fmaf(vq.y, wrow[(qd * 4 + 1) * 16], acc);
                        acc = fmaf(vq.z, wrow[(qd * 4 + 2) * 16], acc);
                        acc = fmaf(vq.w, wrow[(qd * 4 + 3) * 16], acc);
                    }
                }
            }
            Iout[(d * 128 + yo + yl) * 16 + c] = acc;
            float s = acc, q = acc * acc;
            s += __shfl_xor(s, 16, 64); s += __shfl_xor(s, 32, 64);
            q += __shfl_xor(q, 16, 64); q += __shfl_xor(q, 32, 64);
            if ((tid & 63) < 16) {
                atomicAdd(&sred[c], s);
                atomicAdd(&sred[16 + c], q);
            }
            __syncthreads();
            if (tid < 32) atomicAdd(&stO[bank + tid], 120.f * sred[tid]);
            __syncthreads();   // LDS reuse guard before next unit / mini
        }

        // ---- mini units (unit = yt*128 + z) ----
        for (int u = 0; u < 2; ++u) {
            const int unit = blockIdx.x * 2 + u;
            const int bank = (unit & 7) * 32;
            u16*   stage = (u16*)smem_raw;
            float* sredm = (float*)(smem_raw + 27648);
            float* sAm   = (float*)(smem_raw + 27776);
            const int z  = unit & 127;
            const int yt = unit >> 7;
            const int l = tid & 63, w = tid >> 6;
            const int n = l & 15, g = l >> 4, h = g & 1, kxs = g >> 1;
            const int y0 = yt * 16 + w * 4;
            const int y0b = yt * 16;

            if (tid < 32) {
                sredm[tid] = 0.f;
                if (NORM) stat8(stP, tid, sAm);
            }
            __syncthreads();   // sAm ready before staging

            for (int i = tid; i < 1728; i += 256) {
                int r = i >> 5, px = i & 31;
                int kz = r / 18, yr = r - kz * 18;
                int gz = z + kz - 1, gy = y0b + yr - 1;
                uint4 v = make_uint4(0u, 0u, 0u, 0u);
                bool inb = ((unsigned)gz < 128u) & ((unsigned)gy < 128u);
                if (!NORM) {
                    if (inb) v = *(const uint4*)(Min + (((gz << 7) + gy) << 8) + px * 8);
                } else {
                    int x = px >> 1, hh = px & 1;
                    bool realc = (x < 4) | (x >= 8 && x < 12);
                    bool ghost = (x == 4) | (x == 7);
                    if (inb & (realc | ghost)) {
                        float f[8];
                        if (realc) {
                            uint4 raw = *(const uint4*)(Min + (((gz << 7) + gy) << 8) + px * 8);
                            unpack8(raw, f);
                        } else {
                            const float* ip = Iin + ((gz * 128 + gy) * 16 + hh * 8);
                            float4 a  = *(const float4*)(ip);
                            float4 b2 = *(const float4*)(ip + 4);
                            f[0] = a.x;  f[1] = a.y;  f[2] = a.z;  f[3] = a.w;
                            f[4] = b2.x; f[5] = b2.y; f[6] = b2.z; f[7] = b2.w;
                        }
                        float vals[8];
#pragma unroll
                        for (int j = 0; j < 8; j++) {
                            int c = hh * 8 + j;
                            float res = RES ? ldin(gp.proj, c * 16384 + gz * 128 + gy, bf) : 0.f;
                            vals[j] = fmaxf((f[j] - sAm[c]) * sAm[16 + c] + res, 0.f);
                        }
                        u32 pw[4];
#pragma unroll
                        for (int j = 0; j < 4; j++)
                            pw[j] = (u32)f2bf(vals[2*j]) | ((u32)f2bf(vals[2*j+1]) << 16);
                        v = make_uint4(pw[0], pw[1], pw[2], pw[3]);
                    }
                    if (WXB && kz == 1 && yr >= 1 && yr <= 16)
                        *(uint4*)(MXBw + (((z << 7) + gy) << 8) + px * 8) = v;
                }
                *(uint4*)(stage + r * 256 + px * 8) = v;
            }

            s16x8 af[18];
#pragma unroll
            for (int fi = 0; fi < 18; fi++)
                af[fi] = *(const s16x8*)(afragL + (fi * 64 + l) * 8);
            f32x4 binit = *(const f32x4*)(biasL + g * 4);
            __syncthreads();

            f32x4 acc[4];
#pragma unroll
            for (int yl = 0; yl < 4; yl++) acc[yl] = binit;

            const int x0c = n + kxs - 1;
            const int x1c = x0c + 2;
            const bool v0ok = (unsigned)x0c < 16u;
            const bool v1ok = (unsigned)x1c < 16u;

#pragma unroll
            for (int kz = 0; kz < 3; kz++) {
#pragma unroll
                for (int yin = 0; yin < 6; yin++) {
                    const u16* rowp = stage + (kz * 18 + (w << 2) + yin) * 256 + h * 8;
                    uint4 q0 = make_uint4(0u, 0u, 0u, 0u);
                    uint4 q1 = make_uint4(0u, 0u, 0u, 0u);
                    if (v0ok) q0 = *(const uint4*)(rowp + (x0c << 4));
                    if (v1ok) q1 = *(const uint4*)(rowp + (x1c << 4));
                    s16x8 f0 = __builtin_bit_cast(s16x8, q0);
                    s16x8 f1 = __builtin_bit_cast(s16x8, q1);
#pragma unroll
                    for (int ky = 0; ky < 3; ky++) {
                        const int yl = yin - ky;
                        if (yl >= 0 && yl < 4) {
                            acc[yl] = __builtin_amdgcn_mfma_f32_16x16x32_bf16(af[(kz * 3 + ky) * 2],     f0, acc[yl], 0, 0, 0);
                            acc[yl] = __builtin_amdgcn_mfma_f32_16x16x32_bf16(af[(kz * 3 + ky) * 2 + 1], f1, acc[yl], 0, 0, 0);
                        }
                    }
                }
            }

            const float inc = (((n >> 2) & 1) == 0) ? 1.f : 0.f;
            float sr[4] = {0.f, 0.f, 0.f, 0.f}, qr[4] = {0.f, 0.f, 0.f, 0.f};
#pragma unroll
            for (int yl = 0; yl < 4; yl++) {
                const int gy = y0 + yl;
                u32 lo = (u32)f2bf(acc[yl][0]) | ((u32)f2bf(acc[yl][1]) << 16);
                u32 hi = (u32)f2bf(acc[yl][2]) | ((u32)f2bf(acc[yl][3]) << 16);
                *(uint2*)(Mout + (((z << 7) + gy) << 8) + (n << 4) + g * 4) = make_uint2(lo, hi);
#pragma unroll
                for (int r = 0; r < 4; r++) {
                    sr[r] += inc * acc[yl][r];
                    qr[r] = fmaf(inc * acc[yl][r], acc[yl][r], qr[r]);
                }
            }
#pragma unroll
            for (int off = 1; off < 16; off <<= 1) {
#pragma unroll
                for (int r = 0; r < 4; r++) {
                    sr[r] += __shfl_down(sr[r], off, 16);
                    qr[r] += __shfl_down(qr[r], off, 16);
                }
            }
            __syncthreads();
            if (n == 0) {
#pragma unroll
                for (int r = 0; r < 4; r++) {
                    atomicAdd(&sredm[g * 4 + r], sr[r]);
                    atomicAdd(&sredm[16 + g * 4 + r], qr[r]);
                }
            }
            __syncthreads();
            if (tid < 32) atomicAdd(&stO[bank + tid], sredm[tid]);
            __syncthreads();   // guard before next unit restages
        }
        grid.sync();
    }

    // ---------------- fproj stage 1 (units 0..255) ----------------
    {
        float* sA = (float*)smem_raw;
        if (tid < 32) stat8(gp.st + 768, tid, sA);
        __syncthreads();
        for (int u = 0; u < 2; ++u) {
            const int unit = blockIdx.x * 2 + u;
            if (unit >= 256) break;
            const int d = unit >> 1;
            const int half = unit & 1;
            const int yl = tid & 63, y = half * 64 + yl;
            const int h = tid >> 6, c0 = h * 4;

            float v2d[4], row[4];
            {
                const int e = (d * 128 + y) * 16 + c0;
                float4 a = *(const float4*)(gp.I_A + e);
                float4 x = *(const float4*)(gp.I_XB + e);
                float ia[4] = {a.x, a.y, a.z, a.w};
                float xa[4] = {x.x, x.y, x.z, x.w};
#pragma unroll
                for (int cc = 0; cc < 4; cc++) {
                    int c = c0 + cc;
                    v2d[cc] = fmaxf((ia[cc] - sA[c]) * sA[16 + c] + xa[cc], 0.f);
                    row[cc] = 120.f * v2d[cc];
                }
            }
            float colp[8][4];
#pragma unroll
            for (int j = 0; j < 8; j++) {
                const int m = (j < 4) ? j : j + 4;
                const int e = ((d * 128 + y) << 8) + (m << 4) + c0;
                float f4[4], fx[4];
                unpack4(*(const uint2*)(gp.M_A + e), f4);
                unpack4(*(const uint2*)(gp.M_XB + e), fx);
#pragma unroll
                for (int cc = 0; cc < 4; cc++) {
                    int c = c0 + cc;
                    float v = fmaxf((f4[cc] - sA[c]) * sA[16 + c] + fx[cc], 0.f);
                    row[cc] += v;
                    colp[j][cc] = v;
                }
            }
#pragma unroll
            for (int cc = 0; cc < 4; cc++) {
                int oi = ((c0 + cc) * 2) * 16384 + d * 128 + y;
                if (bf) ((u16*)gp.out)[oi] = f2bf(row[cc]); else ((float*)gp.out)[oi] = row[cc];
            }
#pragma unroll
            for (int off = 1; off < 64; off <<= 1) {
#pragma unroll
                for (int cc = 0; cc < 4; cc++) {
                    v2d[cc] += __shfl_down(v2d[cc], off, 64);
#pragma unroll
                    for (int j = 0; j < 8; j++)
                        colp[j][cc] += __shfl_down(colp[j][cc], off, 64);
                }
            }
            if (yl == 0) {
#pragma unroll
                for (int cc = 0; cc < 4; cc++) {
                    atomicAdd(&gp.PS[d * 16 + c0 + cc], v2d[cc]);
#pragma unroll
                    for (int j = 0; j < 8; j++)
                        atomicAdd(&gp.P[(d * 8 + j) * 16 + c0 + cc], colp[j][cc]);
                    if (half == 0) gp.P0[d * 16 + c0 + cc] = colp[0][cc];
                }
            }
        }
    }
    grid.sync();

    // ---------------- fproj stage 2 (units 0..127) ----------------
    for (int u = 0; u < 2; ++u) {
        const int unit = blockIdx.x * 2 + u;
        if (unit >= 128) break;
        const int d = unit;
        for (int i = tid; i < 2048; i += 256) {
            int c = i >> 7, uu = i & 127;
            float v;
            if (uu == 0)        v = gp.P0[d * 16 + c];
            else if (uu < 4)    v = gp.P[(d * 8 + uu) * 16 + c];
            else if (uu >= 124) v = gp.P[(d * 8 + (uu - 120)) * 16 + c];
            else                v = gp.PS[d * 16 + c];
            int oi = (c * 2 + 1) * 16384 + d * 128 + uu;
            if (bf) ((u16*)gp.out)[oi] = f2bf(v); else ((float*)gp.out)[oi] = v;
        }
    }
}

// ===========================================================================
// Fallback path: R13 multi-kernel pipeline (proven 202us).
// ===========================================================================
__global__ __launch_bounds__(256) void wprep_k(
    const void* __restrict__ w0, const void* __restrict__ w1,
    const void* __restrict__ w2, const void* __restrict__ w3,
    const void* __restrict__ b0, const void* __restrict__ b1,
    const void* __restrict__ b2, const void* __restrict__ b3,
    float* __restrict__ st, int* __restrict__ flag,
    float* __restrict__ biasf, float* __restrict__ w2d,
    float* __restrict__ pz, u16* __restrict__ afrag)
{
    const int tid = threadIdx.x;
    const u16* pp = (const u16*)w0;
    int cnt = 0;
    for (int i = 0; i < 32; i++) {
        int e = (pp[2 * i] >> 7) & 0xFF;
        if (e >= 64 && e <= 130) cnt++;
    }
    const int bf = (cnt >= 24) ? 1 : 0;
    const void* WS[4] = {w0, w1, w2, w3};
    const void* BS[4] = {b0, b1, b2, b3};
    const int b = blockIdx.x;

    if (b < 18) {
        int gi = b * 256 + tid;
        int L = gi / 1152, r = gi - L * 1152;
        int fi = r >> 6, l = r & 63;
        int kzky = fi >> 1, grp = fi & 1;
        int kz = kzky / 3, ky = kzky % 3;
        int n = l & 15, g = l >> 4, h = g & 1, kxs = g >> 1;
        int kx = grp * 2 + kxs;
        u16 v[8];
#pragma unroll
        for (int e = 0; e < 8; e++) {
            int ci = h * 8 + e;
            v[e] = (kx <= 2) ? ldbf(WS[L], n * 432 + ci * 27 + kz * 9 + ky * 3 + kx, bf)
                             : (u16)0;
        }
#pragma unroll
        for (int e = 0; e < 8; e++) afrag[gi * 8 + e] = v[e];
    } else if (b == 18) {
        for (int i = tid; i < 1024; i += 256) st[i] = 0.f;
        if (tid == 0) *flag = bf;
        if (tid < 64) biasf[tid] = ldin(BS[tid >> 4], tid & 15, bf);
    } else if (b < 99) {
        int i = (b - 19) * 256 + tid;
        pz[i] = 0.f;
    } else {
        int gi = (b - 99) * 256 + tid;
        int L = gi / 2304, r = gi - L * 2304;
        int tap = r >> 8, ci = (r >> 4) & 15, co = r & 15;
        int kz = tap / 3, ky = tap % 3;
        float s = 0.f;
#pragma unroll
        for (int kx = 0; kx < 3; kx++)
            s += ldin(WS[L], (co * 16 + ci) * 27 + kz * 9 + ky * 3 + kx, bf);
        w2d[gi] = s;
    }
}

template <int SRC0, int NORM, int RES, int WXB>
__global__ __launch_bounds__(256) void layer_k(
    const float* __restrict__ Iin, const u16* __restrict__ Min,
    const void* __restrict__ proj, const float* __restrict__ stP,
    const int* __restrict__ flagp,
    const float* __restrict__ w2dL, const u16* __restrict__ afragL,
    const float* __restrict__ biasL,
    float* __restrict__ Iout, u16* __restrict__ Mout,
    float* __restrict__ IXB, u16* __restrict__ MXB,
    float* __restrict__ st_out)
{
    __shared__ __align__(16) char smem_raw[27904];
    const int tid = threadIdx.x;
    const int bf = (SRC0 || RES) ? *flagp : 0;
    const int bank = (blockIdx.x & 7) * 32;

    if (blockIdx.x < 1024) {
        float* smem = (float*)smem_raw;
        float* wsl  = smem;
        float* pin  = smem + 2304;
        float* sred = smem + 3384;
        float* sA   = smem + 3416;
        const int d  = blockIdx.x >> 3;
        const int yo = (blockIdx.x & 7) * 16;
        if (tid < 32) {
            sred[tid] = 0.f;
            if (NORM) stat8(stP, tid, sA);
        }
        for (int i = tid; i < 576; i += 256)
            *(float4*)(wsl + i * 4) = *(const float4*)(w2dL + i * 4);
        if (NORM) __syncthreads();
        for (int i = tid; i < 864; i += 256) {
            int p = i / 288, r = i - p * 288;
            int row = r >> 4, c = r & 15;
            int zz = d + p - 1, gy = yo + row - 1;
            float v = 0.f;
            if ((unsigned)zz < 128u && (unsigned)gy < 128u) {
                if (SRC0) {
                    v = ldin(proj, c * 16384 + zz * 128 + gy, bf);
                } else {
                    v = Iin[(zz * 128 + gy) * 16 + c];
                    if (NORM) {
                        float res = RES ? ldin(proj, c * 16384 + zz * 128 + gy, bf) : 0.f;
                        v = fmaxf((v - sA[c]) * sA[16 + c] + res, 0.f);
                    }
                    if (WXB && p == 1 && row >= 1 && row <= 16)
                        IXB[(d * 128 + gy) * 16 + c] = v;
                }
            }
            pin[p * 360 + row * 20 + c] = v;
        }
        __syncthreads();

        const int c = tid & 15, yl = tid >> 4;
        float acc = biasL[c];
#pragma unroll
        for (int kz = 0; kz < 3; kz++) {
#pragma unroll
            for (int ky = 0; ky < 3; ky++) {
                const float4* rowb = (const float4*)(pin + kz * 360 + (yl + ky) * 20);
                const float* wrow = wsl + (kz * 3 + ky) * 256 + c;
#pragma unroll
                for (int qd = 0; qd < 4; qd++) {
                    float4 vq = rowb[qd];
                    acc = fmaf(vq.x, wrow[(qd * 4 + 0) * 16], acc);
                    acc = fmaf(vq.y, wrow[(qd * 4 + 1) * 16], acc);
                    acc = fmaf(vq.z, wrow[(qd * 4 + 2) * 16], acc);
                    acc = fmaf(vq.w, wrow[(qd * 4 + 3) * 16], acc);
                }
            }
        }
        Iout[(d * 128 + yo + yl) * 16 + c] = acc;
        float s = acc, q = acc * acc;
        s += __shfl_xor(s, 16, 64); s += __shfl_xor(s, 32, 64);
        q += __shfl_xor(q, 16, 64); q += __shfl_xor(q, 32, 64);
        if ((tid & 63) < 16) {
            atomicAdd(&sred[c], s);
            atomicAdd(&sred[16 + c], q);
        }
        __syncthreads();
        if (tid < 32) atomicAdd(&st_out[bank + tid], 120.f * sred[tid]);
        return;
    }

    u16*   stage = (u16*)smem_raw;
    float* sred  = (float*)(smem_raw + 27648);
    float* sA    = (float*)(smem_raw + 27776);
    const int mb = blockIdx.x - 1024;
    const int z  = mb & 127;
    const int yt = mb >> 7;
    const int l = tid & 63, w = tid >> 6;
    const int n = l & 15, g = l >> 4, h = g & 1, kxs = g >> 1;
    const int y0 = yt * 16 + w * 4;
    const int y0b = yt * 16;

    if (tid < 32) {
        sred[tid] = 0.f;
        if (NORM) stat8(stP, tid, sA);
    }
    if (NORM) __syncthreads();

    for (int i = tid; i < 1728; i += 256) {
        int r = i >> 5, px = i & 31;
        int kz = r / 18, yr = r - kz * 18;
        int gz = z + kz - 1, gy = y0b + yr - 1;
        uint4 v = make_uint4(0u, 0u, 0u, 0u);
        bool inb = ((unsigned)gz < 128u) & ((unsigned)gy < 128u);
        if (SRC0) {
            int x = px >> 1, hh = px & 1;
            bool on = (x <= 4) | (x == 7) | (x >= 8 && x < 12);
            if (inb & on) {
                u32 pw[4];
#pragma unroll
                for (int j = 0; j < 4; j++) {
                    int c0 = hh * 8 + 2 * j;
                    u16 a  = f2bf(ldin(proj, c0 * 16384 + gz * 128 + gy, bf));
                    u16 b2 = f2bf(ldin(proj, (c0 + 1) * 16384 + gz * 128 + gy, bf));
                    pw[j] = (u32)a | ((u32)b2 << 16);
                }
                v = make_uint4(pw[0], pw[1], pw[2], pw[3]);
            }
        } else if (!NORM) {
            if (inb) v = *(const uint4*)(Min + (((gz << 7) + gy) << 8) + px * 8);
        } else {
            int x = px >> 1, hh = px & 1;
            bool realc = (x < 4) | (x >= 8 && x < 12);
            bool ghost = (x == 4) | (x == 7);
            if (inb & (realc | ghost)) {
                float f[8];
                if (realc) {
                    uint4 raw = *(const uint4*)(Min + (((gz << 7) + gy) << 8) + px * 8);
                    unpack8(raw, f);
                } else {
                    const float* ip = Iin + ((gz * 128 + gy) * 16 + hh * 8);
                    float4 a  = *(const float4*)(ip);
                    float4 b2 = *(const float4*)(ip + 4);
                    f[0] = a.x;  f[1] = a.y;  f[2] = a.z;  f[3] = a.w;
                    f[4] = b2.x; f[5] = b2.y; f[6] = b2.z; f[7] = b2.w;
                }
                float vals[8];
#pragma unroll
                for (int j = 0; j < 8; j++) {
                    int c = hh * 8 + j;
                    float res = RES ? ldin(proj, c * 16384 + gz * 128 + gy, bf) : 0.f;
                    vals[j] = fmaxf((f[j] - sA[c]) * sA[16 + c] + res, 0.f);
                }
                u32 pw[4];
#pragma unroll
                for (int j = 0; j < 4; j++)
                    pw[j] = (u32)f2bf(vals[2*j]) | ((u32)f2bf(vals[2*j+1]) << 16);
                v = make_uint4(pw[0], pw[1], pw[2], pw[3]);
            }
            if (WXB && kz == 1 && yr >= 1 && yr <= 16)
                *(uint4*)(MXB + (((z << 7) + gy) << 8) + px * 8) = v;
        }
        *(uint4*)(stage + r * 256 + px * 8) = v;
    }

    s16x8 af[18];
#pragma unroll
    for (int fi = 0; fi < 18; fi++)
        af[fi] = *(const s16x8*)(afragL + (fi * 64 + l) * 8);
    f32x4 binit = *(const f32x4*)(biasL + g * 4);
    __syncthreads();

    f32x4 acc[4];
#pragma unroll
    for (int yl = 0; yl < 4; yl++) acc[yl] = binit;

    const int x0c = n + kxs - 1;
    const int x1c = x0c + 2;
    const bool v0ok = (unsigned)x0c < 16u;
    const bool v1ok = (unsigned)x1c < 16u;

#pragma unroll
    for (int kz = 0; kz < 3; kz++) {
#pragma unroll
        for (int yin = 0; yin < 6; yin++) {
            const u16* rowp = stage + (kz * 18 + (w << 2) + yin) * 256 + h * 8;
            uint4 q0 = make_uint4(0u, 0u, 0u, 0u);
            uint4 q1 = make_uint4(0u, 0u, 0u, 0u);
            if (v0ok) q0 = *(const uint4*)(rowp + (x0c << 4));
            if (v1ok) q1 = *(const uint4*)(rowp + (x1c << 4));
            s16x8 f0 = __builtin_bit_cast(s16x8, q0);
            s16x8 f1 = __builtin_bit_cast(s16x8, q1);
#pragma unroll
            for (int ky = 0; ky < 3; ky++) {
                const int yl = yin - ky;
                if (yl >= 0 && yl < 4) {
                    acc[yl] = __builtin_amdgcn_mfma_f32_16x16x32_bf16(af[(kz * 3 + ky) * 2],     f0, acc[yl], 0, 0, 0);
                    acc[yl] = __builtin_amdgcn_mfma_f32_16x16x32_bf16(af[(kz * 3 + ky) * 2 + 1], f1, acc[yl], 0, 0, 0);
                }
            }
        }
    }

    const float inc = (((n >> 2) & 1) == 0) ? 1.f : 0.f;
    float sr[4] = {0.f, 0.f, 0.f, 0.f}, qr[4] = {0.f, 0.f, 0.f, 0.f};
#pragma unroll
    for (int yl = 0; yl < 4; yl++) {
        const int gy = y0 + yl;
        u32 lo = (u32)f2bf(acc[yl][0]) | ((u32)f2bf(acc[yl][1]) << 16);
        u32 hi = (u32)f2bf(acc[yl][2]) | ((u32)f2bf(acc[yl][3]) << 16);
        *(uint2*)(Mout + (((z << 7) + gy) << 8) + (n << 4) + g * 4) = make_uint2(lo, hi);
#pragma unroll
        for (int r = 0; r < 4; r++) {
            sr[r] += inc * acc[yl][r];
            qr[r] = fmaf(inc * acc[yl][r], acc[yl][r], qr[r]);
        }
    }
#pragma unroll
    for (int off = 1; off < 16; off <<= 1) {
#pragma unroll
        for (int r = 0; r < 4; r++) {
            sr[r] += __shfl_down(sr[r], off, 16);
            qr[r] += __shfl_down(qr[r], off, 16);
        }
    }
    __syncthreads();
    if (n == 0) {
#pragma unroll
        for (int r = 0; r < 4; r++) {
            atomicAdd(&sred[g * 4 + r], sr[r]);
            atomicAdd(&sred[16 + g * 4 + r], qr[r]);
        }
    }
    __syncthreads();
    if (tid < 32) atomicAdd(&st_out[bank + tid], sred[tid]);
}

__global__ __launch_bounds__(256) void fproj1_k(
    const float* __restrict__ I4, const float* __restrict__ IXB,
    const u16* __restrict__ M4, const u16* __restrict__ MXB,
    const float* __restrict__ stL, const int* __restrict__ flagp,
    void* __restrict__ out,
    float* __restrict__ P, float* __restrict__ PS, float* __restrict__ P0)
{
    __shared__ float sA[32];
    const int bf = *flagp;
    const int d = blockIdx.x >> 1;
    const int half = blockIdx.x & 1;
    const int tid = threadIdx.x;
    if (tid < 32) stat8(stL, tid, sA);
    __syncthreads();

    const int yl = tid & 63, y = half * 64 + yl;
    const int h = tid >> 6, c0 = h * 4;

    float v2d[4], row[4];
    {
        const int e = (d * 128 + y) * 16 + c0;
        float4 a = *(const float4*)(I4 + e);
        float4 x = *(const float4*)(IXB + e);
        float ia[4] = {a.x, a.y, a.z, a.w};
        float xa[4] = {x.x, x.y, x.z, x.w};
#pragma unroll
        for (int cc = 0; cc < 4; cc++) {
            int c = c0 + cc;
            v2d[cc] = fmaxf((ia[cc] - sA[c]) * sA[16 + c] + xa[cc], 0.f);
            row[cc] = 120.f * v2d[cc];
        }
    }
    float colp[8][4];
#pragma unroll
    for (int j = 0; j < 8; j++) {
        const int m = (j < 4) ? j : j + 4;
        const int e = ((d * 128 + y) << 8) + (m << 4) + c0;
        float f4[4], fx[4];
        unpack4(*(const uint2*)(M4 + e), f4);
        unpack4(*(const uint2*)(MXB + e), fx);
#pragma unroll
        for (int cc = 0; cc < 4; cc++) {
            int c = c0 + cc;
            float v = fmaxf((f4[cc] - sA[c]) * sA[16 + c] + fx[cc], 0.f);
            row[cc] += v;
            colp[j][cc] = v;
        }
    }
#pragma unroll
    for (int cc = 0; cc < 4; cc++) {
        int oi = ((c0 + cc) * 2) * 16384 + d * 128 + y;
        if (bf) ((u16*)out)[oi] = f2bf(row[cc]); else ((float*)out)[oi] = row[cc];
    }
#pragma unroll
    for (int off = 1; off < 64; off <<= 1) {
#pragma unroll
        for (int cc = 0; cc < 4; cc++) {
            v2d[cc] += __shfl_down(v2d[cc], off, 64);
#pragma unroll
            for (int j = 0; j < 8; j++)
                colp[j][cc] += __shfl_down(colp[j][cc], off, 64);
        }
    }
    if (yl == 0) {
#pragma unroll
        for (int cc = 0; cc < 4; cc++) {
            atomicAdd(&PS[d * 16 + c0 + cc], v2d[cc]);
#pragma unroll
            for (int j = 0; j < 8; j++)
                atomicAdd(&P[(d * 8 + j) * 16 + c0 + cc], colp[j][cc]);
            if (half == 0) P0[d * 16 + c0 + cc] = colp[0][cc];
        }
    }
}

__global__ __launch_bounds__(256) void fproj2_k(
    const float* __restrict__ P, const float* __restrict__ PS,
    const float* __restrict__ P0, const int* __restrict__ flagp,
    void* __restrict__ out)
{
    const int bf = *flagp;
    const int d = blockIdx.x;
    const int tid = threadIdx.x;
    for (int i = tid; i < 2048; i += 256) {
        int c = i >> 7, u = i & 127;
        float v;
        if (u == 0)        v = P0[d * 16 + c];
        else if (u < 4)    v = P[(d * 8 + u) * 16 + c];
        else if (u >= 124) v = P[(d * 8 + (u - 120)) * 16 + c];
        else               v = PS[d * 16 + c];
        int oi = (c * 2 + 1) * 16384 + d * 128 + u;
        if (bf) ((u16*)out)[oi] = f2bf(v); else ((float*)out)[oi] = v;
    }
}

extern "C" void kernel_launch(void* const* d_in, const int* in_sizes, int n_in,
                              void* d_out, int out_size, void* d_ws, size_t ws_size,
                              hipStream_t stream)
{
    if (ws_size < WS_NEED) {
        sentinel_k<<<(out_size + 255) / 256, 256, 0, stream>>>((u16*)d_out, out_size);
        return;
    }
    const void* proj = d_in[0];
    const void* w1 = d_in[1]; const void* b1 = d_in[2];
    const void* w2 = d_in[3]; const void* b2 = d_in[4];
    const void* w3 = d_in[5]; const void* b3 = d_in[6];
    const void* w4 = d_in[7]; const void* b4 = d_in[8];

    float* I_A  = (float*)d_ws;
    float* I_B  = I_A + IN_ELEMS;
    float* I_XB = I_B + IN_ELEMS;
    u16*   M_A  = (u16*)(I_XB + IN_ELEMS);
    u16*   M_B  = M_A + MN_ELEMS;
    u16*   M_XB = M_B + MN_ELEMS;
    float* st    = (float*)(M_XB + MN_ELEMS);   // 1024 (4 layers x 8 banks x 32)
    int*   flag  = (int*)(st + 1024);           // 16
    float* biasf = (float*)(flag + 16);         // 64
    float* w2d   = biasf + 64;                  // 9216
    float* P     = w2d + 9216;                  // 16384
    float* PS    = P + 16384;                   // 2048
    float* P0    = PS + 2048;                   // 2048
    u16*   afrag = (u16*)(P0 + 2048);           // 36864

    // Capture-safe, cached co-residency proof (pure queries, no stream ops).
    static int coop_ok = -1;
    if (coop_ok < 0) {
        int nb = 0;
        if (hipOccupancyMaxActiveBlocksPerMultiprocessor(&nb, fused_k, 256, 0)
                != hipSuccess) nb = 0;
        int dev = 0;
        hipGetDevice(&dev);
        hipDeviceProp_t prop;
        int mp = 0;
        if (hipGetDeviceProperties(&prop, dev) == hipSuccess)
            mp = prop.multiProcessorCount;
        coop_ok = (nb >= 1 && nb * mp >= 512) ? 1 : 0;
    }

    if (coop_ok == 1) {
        KP gp;
        gp.w0 = w1; gp.w1 = w2; gp.w2 = w3; gp.w3 = w4;
        gp.b0 = b1; gp.b1 = b2; gp.b2 = b3; gp.b3 = b4;
        gp.proj = proj;
        gp.I_A = I_A; gp.I_B = I_B; gp.I_XB = I_XB;
        gp.M_A = M_A; gp.M_B = M_B; gp.M_XB = M_XB;
        gp.st = st; gp.biasf = biasf; gp.w2d = w2d;
        gp.P = P; gp.PS = PS; gp.P0 = P0;
        gp.afrag = afrag; gp.out = d_out;
        void* args[] = {(void*)&gp};
        if (hipLaunchCooperativeKernel(fused_k, dim3(512), dim3(256),
                                       args, 0, stream) == hipSuccess)
            return;
        // fall through only if the (pre-validated) launch still failed
    }

    // -------- fallback: R13 multi-kernel path --------
    wprep_k<<<135, 256, 0, stream>>>(w1, w2, w3, w4, b1, b2, b3, b4,
                                     st, flag, biasf, w2d, P, afrag);
    dim3 lg(2048), cb(256);
    layer_k<1,0,0,0><<<lg, cb, 0, stream>>>(I_A, M_A, proj, st, flag,
                                            w2d + 0,    afrag + 0,     biasf + 0,
                                            I_B, M_B, nullptr, nullptr, st + 0);
    layer_k<0,1,0,0><<<lg, cb, 0, stream>>>(I_B, M_B, proj, st + 0, flag,
                                            w2d + 2304, afrag + 9216,  biasf + 16,
                                            I_A, M_A, nullptr, nullptr, st + 256);
    layer_k<0,1,1,1><<<lg, cb, 0, stream>>>(I_A, M_A, proj, st + 256, flag,
                                            w2d + 4608, afrag + 18432, biasf + 32,
                                            I_B, M_B, I_XB, M_XB, st + 512);
    layer_k<0,1,0,0><<<lg, cb, 0, stream>>>(I_B, M_B, proj, st + 512, flag,
                                            w2d + 6912, afrag + 27648, biasf + 48,
                                            I_A, M_A, nullptr, nullptr, st + 768);
    fproj1_k<<<256, cb, 0, stream>>>(I_A, I_XB, M_A, M_XB, st + 768, flag, d_out, P, PS, P0);
    fproj2_k<<<128, cb, 0, stream>>>(P, PS, P0, flag, d_out);
}